// Round 7
// baseline (2212.498 us; speedup 1.0000x reference)
//
#include <hip/hip_runtime.h>
#include <hip/hip_bf16.h>
#include <cstdint>
#include <cstddef>

// ---------------------------------------------------------------------------
// GCNemb: 8-layer GCN. N=100000, E=3200000.
//   - CSR by target; agg(xW)==agg(x)W -> aggregate on smaller side.
//   - bf16 activation storage, fp32 arithmetic (absmax 4.6e-5 vs 6.56e-5 thr).
//   - r6: parallel scan; fused L0/L1/L2/L7.
//   - r7: A/B test on Infinity-Cache residency: L5 agg = 4x128-wide passes
//     (25.6MB window) vs L6 control = 1x256-wide (r6 measured 53% hit there);
//     MFMA GEMM reads B direct from global (kills ~half the 200k LDS bank
//     conflicts/dispatch; B is L2-hot weights); gather unroll 4->8.
// ---------------------------------------------------------------------------

#define TPB 256
#define SI 8                 // scan items per thread
#define STILE (TPB * SI)     // 2048 elements per scan block

typedef short short8 __attribute__((ext_vector_type(8)));
typedef float f32x4 __attribute__((ext_vector_type(4)));

__device__ __forceinline__ float b2f(unsigned short u) {
    union { unsigned int i; float f; } c; c.i = ((unsigned int)u) << 16; return c.f;
}
__device__ __forceinline__ unsigned short f2b(float f) {
    __hip_bfloat16 h = __float2bfloat16(f);
    union { __hip_bfloat16 h; unsigned short u; } c; c.h = h; return c.u;
}

__device__ __forceinline__ void async_copy16(void* lds, const void* g) {
    __builtin_amdgcn_global_load_lds(
        (const __attribute__((address_space(1))) void*)g,
        (__attribute__((address_space(3))) void*)lds,
        16, 0, 0);
}

// ------------------------------ graph prep --------------------------------

__global__ void count_deg_kernel(const int* __restrict__ col, int* __restrict__ deg,
                                 int E, int n) {
    int e = blockIdx.x * blockDim.x + threadIdx.x;
    if (e < E) {
        int c = col[e];
        if ((unsigned)c < (unsigned)n) atomicAdd(&deg[c], 1);
    }
}

__global__ void dinv_kernel(const int* __restrict__ deg, float* __restrict__ dinv, int n) {
    int i = blockIdx.x * blockDim.x + threadIdx.x;
    if (i < n) dinv[i] = 1.0f / sqrtf((float)(deg[i] + 1));  // +1 self-loop
}

// --- parallel exclusive scan of deg -> rowptr/cursor (3 phases) ---
__global__ __launch_bounds__(TPB) void scan_part1(const int* __restrict__ deg,
                                                  int* __restrict__ bsum, int n) {
    int t0 = blockIdx.x * STILE + threadIdx.x * SI;
    int s = 0;
#pragma unroll
    for (int j = 0; j < SI; j++) { int i = t0 + j; if (i < n) s += deg[i]; }
#pragma unroll
    for (int off = 32; off >= 1; off >>= 1) s += __shfl_xor(s, off);
    __shared__ int ws[TPB / 64];
    if ((threadIdx.x & 63) == 0) ws[threadIdx.x >> 6] = s;
    __syncthreads();
    if (threadIdx.x == 0) {
        int tot = 0;
        for (int i = 0; i < TPB / 64; i++) tot += ws[i];
        bsum[blockIdx.x] = tot;
    }
}

__global__ void scan_part2(int* __restrict__ bsum, int nb,
                           int* __restrict__ rowptr, int n) {
    __shared__ int sums[1024];
    int tid = threadIdx.x;
    int v = (tid < nb) ? bsum[tid] : 0;
    sums[tid] = v;
    __syncthreads();
    for (int off = 1; off < 1024; off <<= 1) {
        int t = (tid >= off) ? sums[tid - off] : 0;
        __syncthreads();
        sums[tid] += t;
        __syncthreads();
    }
    if (tid < nb) bsum[tid] = (tid == 0) ? 0 : sums[tid - 1];
    if (tid == 0) rowptr[n] = sums[1023];
}

__global__ __launch_bounds__(TPB) void scan_part3(const int* __restrict__ deg,
                                                  const int* __restrict__ bsum,
                                                  int* __restrict__ rowptr,
                                                  int* __restrict__ cursor, int n) {
    int tid = threadIdx.x;
    int lane = tid & 63, wv = tid >> 6;
    int t0 = blockIdx.x * STILE + tid * SI;
    int v[SI]; int s = 0;
#pragma unroll
    for (int j = 0; j < SI; j++) { int i = t0 + j; v[j] = (i < n) ? deg[i] : 0; s += v[j]; }
    int sc = s;  // inclusive wave scan
#pragma unroll
    for (int off = 1; off < 64; off <<= 1) {
        int t = __shfl_up(sc, off);
        if (lane >= off) sc += t;
    }
    __shared__ int wtot[TPB / 64];
    if (lane == 63) wtot[wv] = sc;
    __syncthreads();
    int woff = 0;
    for (int i = 0; i < wv; i++) woff += wtot[i];
    int off0 = bsum[blockIdx.x] + woff + (sc - s);
#pragma unroll
    for (int j = 0; j < SI; j++) {
        int i = t0 + j;
        if (i < n) { rowptr[i] = off0; cursor[i] = off0; }
        off0 += v[j];
    }
}

// fill CSR with packed (src, dinv[src]) per edge
__global__ void fill_csr_kernel(const int* __restrict__ row, const int* __restrict__ col,
                                const float* __restrict__ dinv,
                                int* __restrict__ cursor, int2* __restrict__ es,
                                int E, int n) {
    int e = blockIdx.x * blockDim.x + threadIdx.x;
    if (e < E) {
        int c = col[e];
        if ((unsigned)c < (unsigned)n) {
            int r = row[e];
            int pos = atomicAdd(&cursor[c], 1);
            if ((unsigned)pos < (unsigned)E) {
                es[pos] = make_int2(r, __float_as_int(dinv[r]));
            }
        }
    }
}

// weight prep: W[K x M] fp32 -> Wt[M x K] bf16
__global__ void convert_wt_kernel(const float* __restrict__ W, unsigned short* __restrict__ Wt,
                                  int K, int M) {
    int idx = blockIdx.x * blockDim.x + threadIdx.x;
    if (idx < K * M) {
        int k = idx / M, m = idx % M;
        Wt[(size_t)m * K + k] = f2b(W[idx]);
    }
}

// ----------------------------- aggregation --------------------------------

template <int VEC> struct Pack;
template <> struct Pack<1> { using T = unsigned short; };
template <> struct Pack<2> { using T = unsigned int; };
template <> struct Pack<4> { using T = uint2; };

// One wave per node; lane owns VEC contiguous bf16 features inside a column
// window starting at wb; full row stride is d. Edge (src,dinv) batch-loaded
// 64-at-a-time (8B coalesced), broadcast via shfl, gathers unrolled 8-wide.
template <int VEC>
__global__ __launch_bounds__(TPB) void agg_win_kernel(
        const unsigned short* __restrict__ x, unsigned short* __restrict__ out,
        const int* __restrict__ rowptr, const int2* __restrict__ es,
        const float* __restrict__ dinv, const float* __restrict__ bias,
        int n, int d, int wb, int relu) {
    using P = typename Pack<VEC>::T;
    int wid  = (blockIdx.x * blockDim.x + threadIdx.x) >> 6;
    int lane = threadIdx.x & 63;
    if (wid >= n) return;
    int start = rowptr[wid], end = rowptr[wid + 1];
    float acc[4][VEC];
#pragma unroll
    for (int g = 0; g < 4; g++)
#pragma unroll
        for (int j = 0; j < VEC; j++) acc[g][j] = 0.f;
    const int fo = wb + lane * VEC;
    union U { P v; unsigned short u[VEC]; };

    for (int base = start; base < end; base += 64) {
        int idx = base + lane;
        int clamped = (idx < end) ? idx : (end - 1);
        int2 ev = es[clamped];
        int   sv = ev.x;
        float dv = (idx < end) ? __int_as_float(ev.y) : 0.f;
        int cnt = end - base; if (cnt > 64) cnt = 64;
        int j = 0;
        for (; j + 8 <= cnt; j += 8) {
            int s[8]; float e[8]; U l[8];
#pragma unroll
            for (int q = 0; q < 8; q++) { s[q] = __shfl(sv, j + q); e[q] = __shfl(dv, j + q); }
#pragma unroll
            for (int q = 0; q < 8; q++) l[q].v = *(const P*)(x + (size_t)s[q] * d + fo);
#pragma unroll
            for (int q = 0; q < 8; q++)
#pragma unroll
                for (int t = 0; t < VEC; t++)
                    acc[q & 3][t] = fmaf(e[q], b2f(l[q].u[t]), acc[q & 3][t]);
        }
        for (; j < cnt; j++) {
            int   s0 = __shfl(sv, j);
            float e0 = __shfl(dv, j);
            U l0; l0.v = *(const P*)(x + (size_t)s0 * d + fo);
#pragma unroll
            for (int t = 0; t < VEC; t++) acc[0][t] = fmaf(e0, b2f(l0.u[t]), acc[0][t]);
        }
    }

    float di = dinv[wid];
    U ls; ls.v = *(const P*)(x + (size_t)wid * d + fo);
    U st;
#pragma unroll
    for (int j = 0; j < VEC; j++) {
        float a = (acc[0][j] + acc[1][j]) + (acc[2][j] + acc[3][j]);
        float v = di * (a + di * b2f(ls.u[j]));
        if (bias) v += bias[fo + j];
        if (relu) v = fmaxf(v, 0.f);
        st.u[j] = f2b(v);
    }
    *(P*)(out + (size_t)wid * d + fo) = st.v;
}

// Fused: agg(64-wide) + [64x64 GEMM] + bias + relu -> bf16 (L1/L2).
// Wave per node; agg parked in wave-local LDS (no barrier: same-wave rw).
__global__ __launch_bounds__(TPB) void agg_gemm64_kernel(
        const unsigned short* __restrict__ x, unsigned short* __restrict__ out,
        const int* __restrict__ rowptr, const int2* __restrict__ es,
        const float* __restrict__ dinv, const float* __restrict__ W,
        const float* __restrict__ bias, int n) {
    __shared__ float Ws[64 * 64];
    __shared__ float aggs[TPB / 64][64];
    const int tid = threadIdx.x;
    for (int i = tid; i < 64 * 64; i += TPB) Ws[i] = W[i];
    __syncthreads();
    int wid  = (blockIdx.x * TPB + tid) >> 6;
    int lane = tid & 63;
    int wv   = tid >> 6;
    if (wid >= n) return;
    int start = rowptr[wid], end = rowptr[wid + 1];
    float acc0 = 0.f, acc1 = 0.f, acc2 = 0.f, acc3 = 0.f;
    for (int base = start; base < end; base += 64) {
        int idx = base + lane;
        int clamped = (idx < end) ? idx : (end - 1);
        int2 ev = es[clamped];
        int   sv = ev.x;
        float dv = (idx < end) ? __int_as_float(ev.y) : 0.f;
        int cnt = end - base; if (cnt > 64) cnt = 64;
        int j = 0;
        for (; j + 4 <= cnt; j += 4) {
            int   s0 = __shfl(sv, j),     s1 = __shfl(sv, j + 1);
            int   s2 = __shfl(sv, j + 2), s3 = __shfl(sv, j + 3);
            float e0 = __shfl(dv, j),     e1 = __shfl(dv, j + 1);
            float e2 = __shfl(dv, j + 2), e3 = __shfl(dv, j + 3);
            acc0 = fmaf(e0, b2f(x[(size_t)s0 * 64 + lane]), acc0);
            acc1 = fmaf(e1, b2f(x[(size_t)s1 * 64 + lane]), acc1);
            acc2 = fmaf(e2, b2f(x[(size_t)s2 * 64 + lane]), acc2);
            acc3 = fmaf(e3, b2f(x[(size_t)s3 * 64 + lane]), acc3);
        }
        for (; j < cnt; j++) {
            int   s0 = __shfl(sv, j);
            float e0 = __shfl(dv, j);
            acc0 = fmaf(e0, b2f(x[(size_t)s0 * 64 + lane]), acc0);
        }
    }
    float di = dinv[wid];
    float a = di * (((acc0 + acc1) + (acc2 + acc3)) + di * b2f(x[(size_t)wid * 64 + lane]));
    aggs[wv][lane] = a;
    // same-wave LDS write->read: lockstep + compiler lgkmcnt, no barrier
    float v = bias[lane];
#pragma unroll 8
    for (int j = 0; j < 64; j++) v = fmaf(aggs[wv][j], Ws[j * 64 + lane], v);
    v = fmaxf(v, 0.f);
    out[(size_t)wid * 64 + lane] = f2b(v);
}

// Wave-per-node, edge-parallel aggregation for tiny dims (fp32 x), with
// optional fused (D -> 64) GEMM + bias + relu -> bf16 output (L0 path).
template <int D, int FUSE64>
__global__ __launch_bounds__(TPB) void agg_small_wave_kernel(
        const float* __restrict__ x, float* __restrict__ outf,
        unsigned short* __restrict__ outb,
        const int* __restrict__ rowptr, const int2* __restrict__ es,
        const float* __restrict__ dinv, const float* __restrict__ bias,
        const float* __restrict__ W, int n, int relu) {
    int wid  = (blockIdx.x * blockDim.x + threadIdx.x) >> 6;
    int lane = threadIdx.x & 63;
    if (wid >= n) return;
    int start = rowptr[wid], end = rowptr[wid + 1];
    float acc[D];
#pragma unroll
    for (int j = 0; j < D; j++) acc[j] = 0.f;
    for (int e = start + lane; e < end; e += 64) {
        int2 ev = es[e];
        int s = ev.x;
        float ds = __int_as_float(ev.y);
#pragma unroll
        for (int j = 0; j < D; j++) acc[j] = fmaf(ds, x[(size_t)s * D + j], acc[j]);
    }
#pragma unroll
    for (int j = 0; j < D; j++) {
#pragma unroll
        for (int off = 32; off >= 1; off >>= 1) acc[j] += __shfl_xor(acc[j], off);
    }
    float di = dinv[wid];
    float aggv[D];
#pragma unroll
    for (int j = 0; j < D; j++) aggv[j] = di * (acc[j] + di * x[(size_t)wid * D + j]);

    if (FUSE64) {
        float v = bias[lane];
#pragma unroll
        for (int j = 0; j < D; j++) v = fmaf(aggv[j], W[j * 64 + lane], v);
        v = fmaxf(v, 0.f);
        outb[(size_t)wid * 64 + lane] = f2b(v);
    } else {
        if (lane < D) {
            float v = aggv[lane];
            if (bias) v += bias[lane];
            if (relu) v = fmaxf(v, 0.f);
            outf[(size_t)wid * D + lane] = v;
        }
    }
}

// Wave-per-node GEMM for L7: pre[n x 2] = A[n x 256](bf16) @ W[256 x 2](fp32)
__global__ __launch_bounds__(TPB) void gemm_dot2_kernel(
        const unsigned short* __restrict__ A, const float* __restrict__ W,
        float* __restrict__ pre, int n) {
    int wid  = (blockIdx.x * blockDim.x + threadIdx.x) >> 6;
    int lane = threadIdx.x & 63;
    if (wid >= n) return;
    union { uint2 v; unsigned short u[4]; } a;
    a.v = *(const uint2*)(A + (size_t)wid * 256 + lane * 4);
    float c0 = 0.f, c1 = 0.f;
#pragma unroll
    for (int j = 0; j < 4; j++) {
        float av = b2f(a.u[j]);
        c0 = fmaf(av, W[(lane * 4 + j) * 2 + 0], c0);
        c1 = fmaf(av, W[(lane * 4 + j) * 2 + 1], c1);
    }
#pragma unroll
    for (int off = 32; off >= 1; off >>= 1) {
        c0 += __shfl_xor(c0, off);
        c1 += __shfl_xor(c1, off);
    }
    if (lane == 0) { pre[(size_t)wid * 2 + 0] = c0; pre[(size_t)wid * 2 + 1] = c1; }
}

// ------------------------------ MFMA GEMM ---------------------------------
// C[nr x M] = A[nr x K](bf16) * Wt[M x K](bf16, pre-transposed) (+bias)(+relu)
// 128x128 tile, BK=32, 2x2 waves x 4x4 frags of v_mfma_f32_16x16x32_bf16.
// A staged via global_load_lds; B frags read DIRECT from global (weights are
// L1/L2-hot; r6 measured 200k LDS bank conflicts/dispatch with B in LDS).
__global__ __launch_bounds__(256) void gemm_mfma_kernel(
        const unsigned short* __restrict__ A, const unsigned short* __restrict__ Wt,
        const float* __restrict__ bias, unsigned short* __restrict__ C,
        int nr, int K, int M, int relu, int addbias) {
    __shared__ alignas(16) short As[128 * 32];
    const int tid  = threadIdx.x;
    const int w    = tid >> 6;
    const int lane = tid & 63;
    const int wr   = w >> 1;
    const int wc   = w & 1;
    const int row0 = blockIdx.x * 128;
    const int col0 = blockIdx.y * 128;

    f32x4 acc[4][4];
#pragma unroll
    for (int i = 0; i < 4; i++)
#pragma unroll
        for (int j = 0; j < 4; j++) acc[i][j] = {0.f, 0.f, 0.f, 0.f};

    const int lrow   = lane >> 2;        // staging: row within 16-row group
    const int lcolB  = (lane & 3) * 16;  // staging: byte offset within 64B row
    const int fm     = lane & 15;        // frag row/col within 16
    const int fq     = lane >> 4;        // k-octet 0..3

    // B frag base pointers (per-lane, advance by kk)
    const unsigned short* wtb[4];
#pragma unroll
    for (int i = 0; i < 4; i++)
        wtb[i] = Wt + (size_t)(col0 + wc * 64 + i * 16 + fm) * K + fq * 8;

    for (int kk = 0; kk < K; kk += 32) {
        // stage A tile: wave w -> rows w*32 .. w*32+31 (2 instrs x 16 rows)
#pragma unroll
        for (int i = 0; i < 2; i++) {
            int r = w * 32 + i * 16 + lrow;
            int grow = row0 + r;
            const char* g = (const char*)A + ((size_t)grow * K + kk) * 2 + lcolB;
            short* lds = &As[(w * 32 + i * 16) * 32];
            if (grow < nr) async_copy16(lds, g);
        }
        // B frags direct from global (L1/L2-hot weights)
        short8 b[4];
#pragma unroll
        for (int i = 0; i < 4; i++) b[i] = *(const short8*)(wtb[i] + kk);
        __syncthreads();  // drains vmcnt for global_load_lds

        short8 a[4];
#pragma unroll
        for (int i = 0; i < 4; i++)
            a[i] = *(const short8*)&As[(wr * 64 + i * 16 + fm) * 32 + fq * 8];
#pragma unroll
        for (int mi = 0; mi < 4; mi++)
#pragma unroll
            for (int ni = 0; ni < 4; ni++)
                acc[mi][ni] = __builtin_amdgcn_mfma_f32_16x16x32_bf16(
                    a[mi], b[ni], acc[mi][ni], 0, 0, 0);
        __syncthreads();
    }

    // epilogue: C/D layout col=lane&15, row=(lane>>4)*4+reg
#pragma unroll
    for (int mi = 0; mi < 4; mi++) {
#pragma unroll
        for (int r = 0; r < 4; r++) {
            int row = row0 + wr * 64 + mi * 16 + fq * 4 + r;
            if (row >= nr) continue;
            size_t rb = (size_t)row * M;
#pragma unroll
            for (int ni = 0; ni < 4; ni++) {
                int col = col0 + wc * 64 + ni * 16 + fm;
                float v = acc[mi][ni][r];
                if (addbias) v += bias[col];
                if (relu) v = fmaxf(v, 0.f);
                C[rb + col] = f2b(v);
            }
        }
    }
}

static inline void launch_gemm_mfma(const unsigned short* A, const unsigned short* Wt,
                                    const float* bias, unsigned short* C,
                                    int nr, int K, int M, int relu, int addbias,
                                    hipStream_t stream) {
    dim3 grid((nr + 127) / 128, M / 128);
    gemm_mfma_kernel<<<grid, 256, 0, stream>>>(A, Wt, bias, C, nr, K, M, relu, addbias);
}

// ------------------------------- driver -----------------------------------

static inline size_t al256(size_t x) { return (x + 255) & ~(size_t)255; }

extern "C" void kernel_launch(void* const* d_in, const int* in_sizes, int n_in,
                              void* d_out, int out_size, void* d_ws, size_t ws_size,
                              hipStream_t stream) {
    const float* x  = (const float*)d_in[0];
    const int*   ei = (const int*)d_in[1];
    const int E = in_sizes[1] / 2;
    const int n = in_sizes[0] / 3;
    const int* rowv = ei;        // sources
    const int* colv = ei + E;    // targets

    const float* Wf[8]; const float* bt[8];
    for (int i = 0; i < 8; i++) { Wf[i] = (const float*)d_in[2 + 2 * i]; bt[i] = (const float*)d_in[3 + 2 * i]; }

    char* p = (char*)d_ws;
    size_t used = 0;
    auto carve = [&](size_t bytes) -> char* {
        char* r = p + used; used += al256(bytes); return r;
    };
    int*   deg    = (int*)carve((size_t)n * 4);
    float* dinv   = (float*)carve((size_t)n * 4);
    int*   rowptr = (int*)carve((size_t)(n + 1) * 4);
    int*   cursor = (int*)carve((size_t)(n + 1) * 4);
    int*   bsum   = (int*)carve(4096 * 4);
    int2*  es     = (int2*)carve((size_t)E * 8);   // packed (src, dinv[src])
    unsigned short* bufA = (unsigned short*)carve((size_t)n * 512 * 2);
    unsigned short* bufB = (unsigned short*)carve((size_t)n * 512 * 2);
    const size_t wt3e = 64 * 128, wt4e = 128 * 1024, wt5e = 1024 * 512, wt6e = 512 * 256;
    unsigned short* wt3 = (unsigned short*)carve((wt3e + wt4e + wt5e + wt6e) * 2);
    unsigned short* wt4 = wt3 + wt3e;
    unsigned short* wt5 = wt4 + wt4e;
    unsigned short* wt6 = wt5 + wt5e;
    size_t avail = (ws_size > used) ? (ws_size - used) : 0;
    int chunk = (int)(avail / (1024 * 2));
    if (chunk > n) chunk = n;
    chunk &= ~127;                  // multiple of 128 for clean MFMA tiles
    if (chunk < 2048) chunk = 2048; // floor
    char* tmp_raw = carve((size_t)chunk * 1024 * 2);
    unsigned short* tmpb = (unsigned short*)tmp_raw;
    float* tmpf = (float*)tmp_raw;   // reused: n x 2 fp32 (L7 pre-agg)

    const int EB = (E + TPB - 1) / TPB;
    const int NB = (n + TPB - 1) / TPB;
    const int NW = (n + 3) / 4;      // wave-per-node kernels, 4 waves/block
    const int SBK = (n + STILE - 1) / STILE;  // scan blocks

    // ---- graph preprocessing ----
    hipMemsetAsync(deg, 0, (size_t)n * 4, stream);
    count_deg_kernel<<<EB, TPB, 0, stream>>>(colv, deg, E, n);
    dinv_kernel<<<NB, TPB, 0, stream>>>(deg, dinv, n);
    scan_part1<<<SBK, TPB, 0, stream>>>(deg, bsum, n);
    scan_part2<<<1, 1024, 0, stream>>>(bsum, SBK, rowptr, n);
    scan_part3<<<SBK, TPB, 0, stream>>>(deg, bsum, rowptr, cursor, n);
    fill_csr_kernel<<<EB, TPB, 0, stream>>>(rowv, colv, dinv, cursor, es, E, n);

    // ---- weight prep ----
    convert_wt_kernel<<<(int)((wt3e + 255) / 256), 256, 0, stream>>>(Wf[3], wt3, 64, 128);
    convert_wt_kernel<<<(int)((wt4e + 255) / 256), 256, 0, stream>>>(Wf[4], wt4, 128, 1024);
    convert_wt_kernel<<<(int)((wt5e + 255) / 256), 256, 0, stream>>>(Wf[5], wt5, 1024, 512);
    convert_wt_kernel<<<(int)((wt6e + 255) / 256), 256, 0, stream>>>(Wf[6], wt6, 512, 256);

    // ---- L0: fused agg(d=3) + (3->64 GEMM) + bias + relu -> bf16 ----
    agg_small_wave_kernel<3, 1><<<NW, TPB, 0, stream>>>(
        x, nullptr, bufA, rowptr, es, dinv, bt[0], Wf[0], n, 1);

    // ---- L1, L2: fused agg + 64x64 GEMM + bias + relu ----
    agg_gemm64_kernel<<<NW, TPB, 0, stream>>>(bufA, bufB, rowptr, es, dinv, Wf[1], bt[1], n);
    agg_gemm64_kernel<<<NW, TPB, 0, stream>>>(bufB, bufA, rowptr, es, dinv, Wf[2], bt[2], n);

    // ---- L3: 64 -> 128 (agg-first, MFMA) ----
    agg_win_kernel<1><<<NW, TPB, 0, stream>>>(bufA, bufB, rowptr, es, dinv, nullptr, n, 64, 0, 0);
    launch_gemm_mfma(bufB, wt3, bt[3], bufA, n, 64, 128, 1, 1, stream);

    // ---- L4+L5 fused: agg on 128, then chunked (relu(.@W4+b4)) @ W5 ----
    agg_win_kernel<2><<<NW, TPB, 0, stream>>>(bufA, bufB, rowptr, es, dinv, nullptr, n, 128, 0, 0);
    for (int r0 = 0; r0 < n; r0 += chunk) {
        int ch = n - r0; if (ch > chunk) ch = chunk;
        launch_gemm_mfma(bufB + (size_t)r0 * 128, wt4, bt[4], tmpb, ch, 128, 1024, 1, 1, stream);
        launch_gemm_mfma(tmpb, wt5, nullptr, bufA + (size_t)r0 * 512, ch, 1024, 512, 0, 0, stream);
    }
    // L5 epilogue: agg on 512 in FOUR 128-wide passes (25.6MB window;
    // EXPERIMENT vs L6's 256-wide control — r6 measured 53% cache hit at 256)
    for (int wpass = 0; wpass < 4; wpass++)
        agg_win_kernel<2><<<NW, TPB, 0, stream>>>(
            bufA, bufB, rowptr, es, dinv, bt[5], n, 512, wpass * 128, 1);

    // ---- L6: 512 -> 256 (matmul-first MFMA, agg on 256 single pass: CONTROL) ----
    launch_gemm_mfma(bufB, wt6, nullptr, bufA, n, 512, 256, 0, 0, stream);
    agg_win_kernel<4><<<NW, TPB, 0, stream>>>(bufA, bufB, rowptr, es, dinv, bt[6], n, 256, 0, 1);

    // ---- L7: wave-dot GEMM (256->2), then agg d=2 + bias, no relu ----
    gemm_dot2_kernel<<<NW, TPB, 0, stream>>>(bufB, Wf[7], tmpf, n);
    agg_small_wave_kernel<2, 0><<<NW, TPB, 0, stream>>>(
        tmpf, (float*)d_out, nullptr, rowptr, es, dinv, bt[7], nullptr, n, 0);
}

// Round 8
// 2188.826 us; speedup vs baseline: 1.0108x; 1.0108x over previous
//
#include <hip/hip_runtime.h>
#include <hip/hip_bf16.h>
#include <cstdint>
#include <cstddef>

// ---------------------------------------------------------------------------
// GCNemb: 8-layer GCN. N=100000, E=3200000.
//   - CSR by target; agg(xW)==agg(x)W -> aggregate on smaller side.
//   - bf16 activation storage, fp32 arithmetic (absmax 4.6e-5 vs 6.56e-5 thr).
//   - r7 findings: 256-wide agg passes are at the random-gather plateau
//     (~3.85 TB/s effective, FETCH fixed, VALU/unroll/window changes neutral
//     or negative). 4x128 split REVERTED (measured 616us vs 442us).
//   - r8: L6-agg fused with L7 256->2 GEMM (in-register dot, saves 102MB
//     round-trip + a dispatch).
// ---------------------------------------------------------------------------

#define TPB 256
#define SI 8                 // scan items per thread
#define STILE (TPB * SI)     // 2048 elements per scan block

typedef short short8 __attribute__((ext_vector_type(8)));
typedef float f32x4 __attribute__((ext_vector_type(4)));

__device__ __forceinline__ float b2f(unsigned short u) {
    union { unsigned int i; float f; } c; c.i = ((unsigned int)u) << 16; return c.f;
}
__device__ __forceinline__ unsigned short f2b(float f) {
    __hip_bfloat16 h = __float2bfloat16(f);
    union { __hip_bfloat16 h; unsigned short u; } c; c.h = h; return c.u;
}

__device__ __forceinline__ void async_copy16(void* lds, const void* g) {
    __builtin_amdgcn_global_load_lds(
        (const __attribute__((address_space(1))) void*)g,
        (__attribute__((address_space(3))) void*)lds,
        16, 0, 0);
}

// ------------------------------ graph prep --------------------------------

__global__ void count_deg_kernel(const int* __restrict__ col, int* __restrict__ deg,
                                 int E, int n) {
    int e = blockIdx.x * blockDim.x + threadIdx.x;
    if (e < E) {
        int c = col[e];
        if ((unsigned)c < (unsigned)n) atomicAdd(&deg[c], 1);
    }
}

__global__ void dinv_kernel(const int* __restrict__ deg, float* __restrict__ dinv, int n) {
    int i = blockIdx.x * blockDim.x + threadIdx.x;
    if (i < n) dinv[i] = 1.0f / sqrtf((float)(deg[i] + 1));  // +1 self-loop
}

// --- parallel exclusive scan of deg -> rowptr/cursor (3 phases) ---
__global__ __launch_bounds__(TPB) void scan_part1(const int* __restrict__ deg,
                                                  int* __restrict__ bsum, int n) {
    int t0 = blockIdx.x * STILE + threadIdx.x * SI;
    int s = 0;
#pragma unroll
    for (int j = 0; j < SI; j++) { int i = t0 + j; if (i < n) s += deg[i]; }
#pragma unroll
    for (int off = 32; off >= 1; off >>= 1) s += __shfl_xor(s, off);
    __shared__ int ws[TPB / 64];
    if ((threadIdx.x & 63) == 0) ws[threadIdx.x >> 6] = s;
    __syncthreads();
    if (threadIdx.x == 0) {
        int tot = 0;
        for (int i = 0; i < TPB / 64; i++) tot += ws[i];
        bsum[blockIdx.x] = tot;
    }
}

__global__ void scan_part2(int* __restrict__ bsum, int nb,
                           int* __restrict__ rowptr, int n) {
    __shared__ int sums[1024];
    int tid = threadIdx.x;
    int v = (tid < nb) ? bsum[tid] : 0;
    sums[tid] = v;
    __syncthreads();
    for (int off = 1; off < 1024; off <<= 1) {
        int t = (tid >= off) ? sums[tid - off] : 0;
        __syncthreads();
        sums[tid] += t;
        __syncthreads();
    }
    if (tid < nb) bsum[tid] = (tid == 0) ? 0 : sums[tid - 1];
    if (tid == 0) rowptr[n] = sums[1023];
}

__global__ __launch_bounds__(TPB) void scan_part3(const int* __restrict__ deg,
                                                  const int* __restrict__ bsum,
                                                  int* __restrict__ rowptr,
                                                  int* __restrict__ cursor, int n) {
    int tid = threadIdx.x;
    int lane = tid & 63, wv = tid >> 6;
    int t0 = blockIdx.x * STILE + tid * SI;
    int v[SI]; int s = 0;
#pragma unroll
    for (int j = 0; j < SI; j++) { int i = t0 + j; v[j] = (i < n) ? deg[i] : 0; s += v[j]; }
    int sc = s;  // inclusive wave scan
#pragma unroll
    for (int off = 1; off < 64; off <<= 1) {
        int t = __shfl_up(sc, off);
        if (lane >= off) sc += t;
    }
    __shared__ int wtot[TPB / 64];
    if (lane == 63) wtot[wv] = sc;
    __syncthreads();
    int woff = 0;
    for (int i = 0; i < wv; i++) woff += wtot[i];
    int off0 = bsum[blockIdx.x] + woff + (sc - s);
#pragma unroll
    for (int j = 0; j < SI; j++) {
        int i = t0 + j;
        if (i < n) { rowptr[i] = off0; cursor[i] = off0; }
        off0 += v[j];
    }
}

// fill CSR with packed (src, dinv[src]) per edge
__global__ void fill_csr_kernel(const int* __restrict__ row, const int* __restrict__ col,
                                const float* __restrict__ dinv,
                                int* __restrict__ cursor, int2* __restrict__ es,
                                int E, int n) {
    int e = blockIdx.x * blockDim.x + threadIdx.x;
    if (e < E) {
        int c = col[e];
        if ((unsigned)c < (unsigned)n) {
            int r = row[e];
            int pos = atomicAdd(&cursor[c], 1);
            if ((unsigned)pos < (unsigned)E) {
                es[pos] = make_int2(r, __float_as_int(dinv[r]));
            }
        }
    }
}

// weight prep: W[K x M] fp32 -> Wt[M x K] bf16
__global__ void convert_wt_kernel(const float* __restrict__ W, unsigned short* __restrict__ Wt,
                                  int K, int M) {
    int idx = blockIdx.x * blockDim.x + threadIdx.x;
    if (idx < K * M) {
        int k = idx / M, m = idx % M;
        Wt[(size_t)m * K + k] = f2b(W[idx]);
    }
}

// ----------------------------- aggregation --------------------------------

template <int VEC> struct Pack;
template <> struct Pack<1> { using T = unsigned short; };
template <> struct Pack<2> { using T = unsigned int; };
template <> struct Pack<4> { using T = uint2; };

// One wave per node; lane owns VEC contiguous bf16 features inside a column
// window starting at wb; full row stride is d. Edge (src,dinv) batch-loaded
// 64-at-a-time (8B coalesced), broadcast via shfl, gathers unrolled 8-wide.
template <int VEC>
__global__ __launch_bounds__(TPB) void agg_win_kernel(
        const unsigned short* __restrict__ x, unsigned short* __restrict__ out,
        const int* __restrict__ rowptr, const int2* __restrict__ es,
        const float* __restrict__ dinv, const float* __restrict__ bias,
        int n, int d, int wb, int relu) {
    using P = typename Pack<VEC>::T;
    int wid  = (blockIdx.x * blockDim.x + threadIdx.x) >> 6;
    int lane = threadIdx.x & 63;
    if (wid >= n) return;
    int start = rowptr[wid], end = rowptr[wid + 1];
    float acc[4][VEC];
#pragma unroll
    for (int g = 0; g < 4; g++)
#pragma unroll
        for (int j = 0; j < VEC; j++) acc[g][j] = 0.f;
    const int fo = wb + lane * VEC;
    union U { P v; unsigned short u[VEC]; };

    for (int base = start; base < end; base += 64) {
        int idx = base + lane;
        int clamped = (idx < end) ? idx : (end - 1);
        int2 ev = es[clamped];
        int   sv = ev.x;
        float dv = (idx < end) ? __int_as_float(ev.y) : 0.f;
        int cnt = end - base; if (cnt > 64) cnt = 64;
        int j = 0;
        for (; j + 8 <= cnt; j += 8) {
            int s[8]; float e[8]; U l[8];
#pragma unroll
            for (int q = 0; q < 8; q++) { s[q] = __shfl(sv, j + q); e[q] = __shfl(dv, j + q); }
#pragma unroll
            for (int q = 0; q < 8; q++) l[q].v = *(const P*)(x + (size_t)s[q] * d + fo);
#pragma unroll
            for (int q = 0; q < 8; q++)
#pragma unroll
                for (int t = 0; t < VEC; t++)
                    acc[q & 3][t] = fmaf(e[q], b2f(l[q].u[t]), acc[q & 3][t]);
        }
        for (; j < cnt; j++) {
            int   s0 = __shfl(sv, j);
            float e0 = __shfl(dv, j);
            U l0; l0.v = *(const P*)(x + (size_t)s0 * d + fo);
#pragma unroll
            for (int t = 0; t < VEC; t++) acc[0][t] = fmaf(e0, b2f(l0.u[t]), acc[0][t]);
        }
    }

    float di = dinv[wid];
    U ls; ls.v = *(const P*)(x + (size_t)wid * d + fo);
    U st;
#pragma unroll
    for (int j = 0; j < VEC; j++) {
        float a = (acc[0][j] + acc[1][j]) + (acc[2][j] + acc[3][j]);
        float v = di * (a + di * b2f(ls.u[j]));
        if (bias) v += bias[fo + j];
        if (relu) v = fmaxf(v, 0.f);
        st.u[j] = f2b(v);
    }
    *(P*)(out + (size_t)wid * d + fo) = st.v;
}

// Fused L6-agg(256-wide) + bias + relu + L7 GEMM (256->2): per-node dot
// against W7 in registers, butterfly-reduce, write 2 fp32. No 51MB roundtrip.
__global__ __launch_bounds__(TPB) void agg_dot2_kernel(
        const unsigned short* __restrict__ x,
        const int* __restrict__ rowptr, const int2* __restrict__ es,
        const float* __restrict__ dinv, const float* __restrict__ bias6,
        const float* __restrict__ W7, float* __restrict__ pre, int n) {
    int wid  = (blockIdx.x * blockDim.x + threadIdx.x) >> 6;
    int lane = threadIdx.x & 63;
    if (wid >= n) return;
    int start = rowptr[wid], end = rowptr[wid + 1];
    float acc[4][4];
#pragma unroll
    for (int g = 0; g < 4; g++)
#pragma unroll
        for (int j = 0; j < 4; j++) acc[g][j] = 0.f;
    const int fo = lane * 4;
    union U { uint2 v; unsigned short u[4]; };

    for (int base = start; base < end; base += 64) {
        int idx = base + lane;
        int clamped = (idx < end) ? idx : (end - 1);
        int2 ev = es[clamped];
        int   sv = ev.x;
        float dv = (idx < end) ? __int_as_float(ev.y) : 0.f;
        int cnt = end - base; if (cnt > 64) cnt = 64;
        int j = 0;
        for (; j + 8 <= cnt; j += 8) {
            int s[8]; float e[8]; U l[8];
#pragma unroll
            for (int q = 0; q < 8; q++) { s[q] = __shfl(sv, j + q); e[q] = __shfl(dv, j + q); }
#pragma unroll
            for (int q = 0; q < 8; q++) l[q].v = *(const uint2*)(x + (size_t)s[q] * 256 + fo);
#pragma unroll
            for (int q = 0; q < 8; q++)
#pragma unroll
                for (int t = 0; t < 4; t++)
                    acc[q & 3][t] = fmaf(e[q], b2f(l[q].u[t]), acc[q & 3][t]);
        }
        for (; j < cnt; j++) {
            int   s0 = __shfl(sv, j);
            float e0 = __shfl(dv, j);
            U l0; l0.v = *(const uint2*)(x + (size_t)s0 * 256 + fo);
#pragma unroll
            for (int t = 0; t < 4; t++) acc[0][t] = fmaf(e0, b2f(l0.u[t]), acc[0][t]);
        }
    }

    float di = dinv[wid];
    U ls; ls.v = *(const uint2*)(x + (size_t)wid * 256 + fo);
    float c0 = 0.f, c1 = 0.f;
#pragma unroll
    for (int j = 0; j < 4; j++) {
        float a = (acc[0][j] + acc[1][j]) + (acc[2][j] + acc[3][j]);
        float h = di * (a + di * b2f(ls.u[j])) + bias6[fo + j];
        h = fmaxf(h, 0.f);                       // L6 output (fp32, unrounded)
        c0 = fmaf(h, W7[(fo + j) * 2 + 0], c0);  // L7 dot
        c1 = fmaf(h, W7[(fo + j) * 2 + 1], c1);
    }
#pragma unroll
    for (int off = 32; off >= 1; off >>= 1) {
        c0 += __shfl_xor(c0, off);
        c1 += __shfl_xor(c1, off);
    }
    if (lane == 0) { pre[(size_t)wid * 2 + 0] = c0; pre[(size_t)wid * 2 + 1] = c1; }
}

// Fused: agg(64-wide) + [64x64 GEMM] + bias + relu -> bf16 (L1/L2).
// Wave per node; agg parked in wave-local LDS (no barrier: same-wave rw).
__global__ __launch_bounds__(TPB) void agg_gemm64_kernel(
        const unsigned short* __restrict__ x, unsigned short* __restrict__ out,
        const int* __restrict__ rowptr, const int2* __restrict__ es,
        const float* __restrict__ dinv, const float* __restrict__ W,
        const float* __restrict__ bias, int n) {
    __shared__ float Ws[64 * 64];
    __shared__ float aggs[TPB / 64][64];
    const int tid = threadIdx.x;
    for (int i = tid; i < 64 * 64; i += TPB) Ws[i] = W[i];
    __syncthreads();
    int wid  = (blockIdx.x * TPB + tid) >> 6;
    int lane = tid & 63;
    int wv   = tid >> 6;
    if (wid >= n) return;
    int start = rowptr[wid], end = rowptr[wid + 1];
    float acc0 = 0.f, acc1 = 0.f, acc2 = 0.f, acc3 = 0.f;
    for (int base = start; base < end; base += 64) {
        int idx = base + lane;
        int clamped = (idx < end) ? idx : (end - 1);
        int2 ev = es[clamped];
        int   sv = ev.x;
        float dv = (idx < end) ? __int_as_float(ev.y) : 0.f;
        int cnt = end - base; if (cnt > 64) cnt = 64;
        int j = 0;
        for (; j + 4 <= cnt; j += 4) {
            int   s0 = __shfl(sv, j),     s1 = __shfl(sv, j + 1);
            int   s2 = __shfl(sv, j + 2), s3 = __shfl(sv, j + 3);
            float e0 = __shfl(dv, j),     e1 = __shfl(dv, j + 1);
            float e2 = __shfl(dv, j + 2), e3 = __shfl(dv, j + 3);
            acc0 = fmaf(e0, b2f(x[(size_t)s0 * 64 + lane]), acc0);
            acc1 = fmaf(e1, b2f(x[(size_t)s1 * 64 + lane]), acc1);
            acc2 = fmaf(e2, b2f(x[(size_t)s2 * 64 + lane]), acc2);
            acc3 = fmaf(e3, b2f(x[(size_t)s3 * 64 + lane]), acc3);
        }
        for (; j < cnt; j++) {
            int   s0 = __shfl(sv, j);
            float e0 = __shfl(dv, j);
            acc0 = fmaf(e0, b2f(x[(size_t)s0 * 64 + lane]), acc0);
        }
    }
    float di = dinv[wid];
    float a = di * (((acc0 + acc1) + (acc2 + acc3)) + di * b2f(x[(size_t)wid * 64 + lane]));
    aggs[wv][lane] = a;
    // same-wave LDS write->read: lockstep + compiler lgkmcnt, no barrier
    float v = bias[lane];
#pragma unroll 8
    for (int j = 0; j < 64; j++) v = fmaf(aggs[wv][j], Ws[j * 64 + lane], v);
    v = fmaxf(v, 0.f);
    out[(size_t)wid * 64 + lane] = f2b(v);
}

// Wave-per-node, edge-parallel aggregation for tiny dims (fp32 x), with
// optional fused (D -> 64) GEMM + bias + relu -> bf16 output (L0 path).
template <int D, int FUSE64>
__global__ __launch_bounds__(TPB) void agg_small_wave_kernel(
        const float* __restrict__ x, float* __restrict__ outf,
        unsigned short* __restrict__ outb,
        const int* __restrict__ rowptr, const int2* __restrict__ es,
        const float* __restrict__ dinv, const float* __restrict__ bias,
        const float* __restrict__ W, int n, int relu) {
    int wid  = (blockIdx.x * blockDim.x + threadIdx.x) >> 6;
    int lane = threadIdx.x & 63;
    if (wid >= n) return;
    int start = rowptr[wid], end = rowptr[wid + 1];
    float acc[D];
#pragma unroll
    for (int j = 0; j < D; j++) acc[j] = 0.f;
    for (int e = start + lane; e < end; e += 64) {
        int2 ev = es[e];
        int s = ev.x;
        float ds = __int_as_float(ev.y);
#pragma unroll
        for (int j = 0; j < D; j++) acc[j] = fmaf(ds, x[(size_t)s * D + j], acc[j]);
    }
#pragma unroll
    for (int j = 0; j < D; j++) {
#pragma unroll
        for (int off = 32; off >= 1; off >>= 1) acc[j] += __shfl_xor(acc[j], off);
    }
    float di = dinv[wid];
    float aggv[D];
#pragma unroll
    for (int j = 0; j < D; j++) aggv[j] = di * (acc[j] + di * x[(size_t)wid * D + j]);

    if (FUSE64) {
        float v = bias[lane];
#pragma unroll
        for (int j = 0; j < D; j++) v = fmaf(aggv[j], W[j * 64 + lane], v);
        v = fmaxf(v, 0.f);
        outb[(size_t)wid * 64 + lane] = f2b(v);
    } else {
        if (lane < D) {
            float v = aggv[lane];
            if (bias) v += bias[lane];
            if (relu) v = fmaxf(v, 0.f);
            outf[(size_t)wid * D + lane] = v;
        }
    }
}

// ------------------------------ MFMA GEMM ---------------------------------
// C[nr x M] = A[nr x K](bf16) * Wt[M x K](bf16, pre-transposed) (+bias)(+relu)
// 128x128 tile, BK=32, 2x2 waves x 4x4 frags of v_mfma_f32_16x16x32_bf16.
// A staged via global_load_lds; B frags read DIRECT from global (L2-hot).
__global__ __launch_bounds__(256) void gemm_mfma_kernel(
        const unsigned short* __restrict__ A, const unsigned short* __restrict__ Wt,
        const float* __restrict__ bias, unsigned short* __restrict__ C,
        int nr, int K, int M, int relu, int addbias) {
    __shared__ alignas(16) short As[128 * 32];
    const int tid  = threadIdx.x;
    const int w    = tid >> 6;
    const int lane = tid & 63;
    const int wr   = w >> 1;
    const int wc   = w & 1;
    const int row0 = blockIdx.x * 128;
    const int col0 = blockIdx.y * 128;

    f32x4 acc[4][4];
#pragma unroll
    for (int i = 0; i < 4; i++)
#pragma unroll
        for (int j = 0; j < 4; j++) acc[i][j] = {0.f, 0.f, 0.f, 0.f};

    const int lrow   = lane >> 2;
    const int lcolB  = (lane & 3) * 16;
    const int fm     = lane & 15;
    const int fq     = lane >> 4;

    const unsigned short* wtb[4];
#pragma unroll
    for (int i = 0; i < 4; i++)
        wtb[i] = Wt + (size_t)(col0 + wc * 64 + i * 16 + fm) * K + fq * 8;

    for (int kk = 0; kk < K; kk += 32) {
#pragma unroll
        for (int i = 0; i < 2; i++) {
            int r = w * 32 + i * 16 + lrow;
            int grow = row0 + r;
            const char* g = (const char*)A + ((size_t)grow * K + kk) * 2 + lcolB;
            short* lds = &As[(w * 32 + i * 16) * 32];
            if (grow < nr) async_copy16(lds, g);
        }
        short8 b[4];
#pragma unroll
        for (int i = 0; i < 4; i++) b[i] = *(const short8*)(wtb[i] + kk);
        __syncthreads();

        short8 a[4];
#pragma unroll
        for (int i = 0; i < 4; i++)
            a[i] = *(const short8*)&As[(wr * 64 + i * 16 + fm) * 32 + fq * 8];
#pragma unroll
        for (int mi = 0; mi < 4; mi++)
#pragma unroll
            for (int ni = 0; ni < 4; ni++)
                acc[mi][ni] = __builtin_amdgcn_mfma_f32_16x16x32_bf16(
                    a[mi], b[ni], acc[mi][ni], 0, 0, 0);
        __syncthreads();
    }

#pragma unroll
    for (int mi = 0; mi < 4; mi++) {
#pragma unroll
        for (int r = 0; r < 4; r++) {
            int row = row0 + wr * 64 + mi * 16 + fq * 4 + r;
            if (row >= nr) continue;
            size_t rb = (size_t)row * M;
#pragma unroll
            for (int ni = 0; ni < 4; ni++) {
                int col = col0 + wc * 64 + ni * 16 + fm;
                float v = acc[mi][ni][r];
                if (addbias) v += bias[col];
                if (relu) v = fmaxf(v, 0.f);
                C[rb + col] = f2b(v);
            }
        }
    }
}

static inline void launch_gemm_mfma(const unsigned short* A, const unsigned short* Wt,
                                    const float* bias, unsigned short* C,
                                    int nr, int K, int M, int relu, int addbias,
                                    hipStream_t stream) {
    dim3 grid((nr + 127) / 128, M / 128);
    gemm_mfma_kernel<<<grid, 256, 0, stream>>>(A, Wt, bias, C, nr, K, M, relu, addbias);
}

// ------------------------------- driver -----------------------------------

static inline size_t al256(size_t x) { return (x + 255) & ~(size_t)255; }

extern "C" void kernel_launch(void* const* d_in, const int* in_sizes, int n_in,
                              void* d_out, int out_size, void* d_ws, size_t ws_size,
                              hipStream_t stream) {
    const float* x  = (const float*)d_in[0];
    const int*   ei = (const int*)d_in[1];
    const int E = in_sizes[1] / 2;
    const int n = in_sizes[0] / 3;
    const int* rowv = ei;        // sources
    const int* colv = ei + E;    // targets

    const float* Wf[8]; const float* bt[8];
    for (int i = 0; i < 8; i++) { Wf[i] = (const float*)d_in[2 + 2 * i]; bt[i] = (const float*)d_in[3 + 2 * i]; }

    char* p = (char*)d_ws;
    size_t used = 0;
    auto carve = [&](size_t bytes) -> char* {
        char* r = p + used; used += al256(bytes); return r;
    };
    int*   deg    = (int*)carve((size_t)n * 4);
    float* dinv   = (float*)carve((size_t)n * 4);
    int*   rowptr = (int*)carve((size_t)(n + 1) * 4);
    int*   cursor = (int*)carve((size_t)(n + 1) * 4);
    int*   bsum   = (int*)carve(4096 * 4);
    int2*  es     = (int2*)carve((size_t)E * 8);   // packed (src, dinv[src])
    unsigned short* bufA = (unsigned short*)carve((size_t)n * 512 * 2);
    unsigned short* bufB = (unsigned short*)carve((size_t)n * 512 * 2);
    const size_t wt3e = 64 * 128, wt4e = 128 * 1024, wt5e = 1024 * 512, wt6e = 512 * 256;
    unsigned short* wt3 = (unsigned short*)carve((wt3e + wt4e + wt5e + wt6e) * 2);
    unsigned short* wt4 = wt3 + wt3e;
    unsigned short* wt5 = wt4 + wt4e;
    unsigned short* wt6 = wt5 + wt5e;
    size_t avail = (ws_size > used) ? (ws_size - used) : 0;
    int chunk = (int)(avail / (1024 * 2));
    if (chunk > n) chunk = n;
    chunk &= ~127;                  // multiple of 128 for clean MFMA tiles
    if (chunk < 2048) chunk = 2048; // floor
    char* tmp_raw = carve((size_t)chunk * 1024 * 2);
    unsigned short* tmpb = (unsigned short*)tmp_raw;
    float* tmpf = (float*)tmp_raw;   // reused: n x 2 fp32 (L7 pre-agg)

    const int EB = (E + TPB - 1) / TPB;
    const int NB = (n + TPB - 1) / TPB;
    const int NW = (n + 3) / 4;      // wave-per-node kernels, 4 waves/block
    const int SBK = (n + STILE - 1) / STILE;  // scan blocks

    // ---- graph preprocessing ----
    hipMemsetAsync(deg, 0, (size_t)n * 4, stream);
    count_deg_kernel<<<EB, TPB, 0, stream>>>(colv, deg, E, n);
    dinv_kernel<<<NB, TPB, 0, stream>>>(deg, dinv, n);
    scan_part1<<<SBK, TPB, 0, stream>>>(deg, bsum, n);
    scan_part2<<<1, 1024, 0, stream>>>(bsum, SBK, rowptr, n);
    scan_part3<<<SBK, TPB, 0, stream>>>(deg, bsum, rowptr, cursor, n);
    fill_csr_kernel<<<EB, TPB, 0, stream>>>(rowv, colv, dinv, cursor, es, E, n);

    // ---- weight prep ----
    convert_wt_kernel<<<(int)((wt3e + 255) / 256), 256, 0, stream>>>(Wf[3], wt3, 64, 128);
    convert_wt_kernel<<<(int)((wt4e + 255) / 256), 256, 0, stream>>>(Wf[4], wt4, 128, 1024);
    convert_wt_kernel<<<(int)((wt5e + 255) / 256), 256, 0, stream>>>(Wf[5], wt5, 1024, 512);
    convert_wt_kernel<<<(int)((wt6e + 255) / 256), 256, 0, stream>>>(Wf[6], wt6, 512, 256);

    // ---- L0: fused agg(d=3) + (3->64 GEMM) + bias + relu -> bf16 ----
    agg_small_wave_kernel<3, 1><<<NW, TPB, 0, stream>>>(
        x, nullptr, bufA, rowptr, es, dinv, bt[0], Wf[0], n, 1);

    // ---- L1, L2: fused agg + 64x64 GEMM + bias + relu ----
    agg_gemm64_kernel<<<NW, TPB, 0, stream>>>(bufA, bufB, rowptr, es, dinv, Wf[1], bt[1], n);
    agg_gemm64_kernel<<<NW, TPB, 0, stream>>>(bufB, bufA, rowptr, es, dinv, Wf[2], bt[2], n);

    // ---- L3: 64 -> 128 (agg-first, MFMA) ----
    agg_win_kernel<1><<<NW, TPB, 0, stream>>>(bufA, bufB, rowptr, es, dinv, nullptr, n, 64, 0, 0);
    launch_gemm_mfma(bufB, wt3, bt[3], bufA, n, 64, 128, 1, 1, stream);

    // ---- L4+L5 fused: agg on 128, then chunked (relu(.@W4+b4)) @ W5 ----
    agg_win_kernel<2><<<NW, TPB, 0, stream>>>(bufA, bufB, rowptr, es, dinv, nullptr, n, 128, 0, 0);
    for (int r0 = 0; r0 < n; r0 += chunk) {
        int ch = n - r0; if (ch > chunk) ch = chunk;
        launch_gemm_mfma(bufB + (size_t)r0 * 128, wt4, bt[4], tmpb, ch, 128, 1024, 1, 1, stream);
        launch_gemm_mfma(tmpb, wt5, nullptr, bufA + (size_t)r0 * 512, ch, 1024, 512, 0, 0, stream);
    }
    // L5 epilogue: agg on 512 in TWO 256-wide passes (r7: 4x128 measured worse)
    agg_win_kernel<4><<<NW, TPB, 0, stream>>>(bufA, bufB, rowptr, es, dinv, bt[5], n, 512, 0, 1);
    agg_win_kernel<4><<<NW, TPB, 0, stream>>>(bufA, bufB, rowptr, es, dinv, bt[5], n, 512, 256, 1);

    // ---- L6: 512 -> 256 (MFMA), then fused agg(256)+bias+relu+L7 dot -> pre ----
    launch_gemm_mfma(bufB, wt6, nullptr, bufA, n, 512, 256, 0, 0, stream);
    agg_dot2_kernel<<<NW, TPB, 0, stream>>>(bufA, rowptr, es, dinv, bt[6], Wf[7], tmpf, n);

    // ---- L7 epilogue: agg d=2 + bias, no relu -> d_out ----
    agg_small_wave_kernel<2, 0><<<NW, TPB, 0, stream>>>(
        tmpf, (float*)d_out, nullptr, rowptr, es, dinv, bt[7], nullptr, n, 0);
}

// Round 9
// 2008.700 us; speedup vs baseline: 1.1015x; 1.0897x over previous
//
#include <hip/hip_runtime.h>
#include <hip/hip_bf16.h>
#include <cstdint>
#include <cstddef>

// ---------------------------------------------------------------------------
// GCNemb: 8-layer GCN. N=100000, E=3200000.
//   - CSR by target; agg(xW)==agg(x)W -> aggregate on smaller side.
//   - bf16 activation storage, fp32 arithmetic (absmax 4.6e-5 vs 6.56e-5 thr).
//   - Gather plateau (measured r4-r8): 256-wide agg passes pin at ~3.87 TB/s,
//     778MB FETCH; unroll depth / window width / packed edges don't move it.
//   - r9: GEMM B-path back to LDS staging (r6->r8 A/B: B-direct from global
//     cost ~+150us despite LDS bank conflicts); dinv folded into scan_part3.
// ---------------------------------------------------------------------------

#define TPB 256
#define SI 8                 // scan items per thread
#define STILE (TPB * SI)     // 2048 elements per scan block

typedef short short8 __attribute__((ext_vector_type(8)));
typedef float f32x4 __attribute__((ext_vector_type(4)));

__device__ __forceinline__ float b2f(unsigned short u) {
    union { unsigned int i; float f; } c; c.i = ((unsigned int)u) << 16; return c.f;
}
__device__ __forceinline__ unsigned short f2b(float f) {
    __hip_bfloat16 h = __float2bfloat16(f);
    union { __hip_bfloat16 h; unsigned short u; } c; c.h = h; return c.u;
}

__device__ __forceinline__ void async_copy16(void* lds, const void* g) {
    __builtin_amdgcn_global_load_lds(
        (const __attribute__((address_space(1))) void*)g,
        (__attribute__((address_space(3))) void*)lds,
        16, 0, 0);
}

// ------------------------------ graph prep --------------------------------

__global__ void count_deg_kernel(const int* __restrict__ col, int* __restrict__ deg,
                                 int E, int n) {
    int e = blockIdx.x * blockDim.x + threadIdx.x;
    if (e < E) {
        int c = col[e];
        if ((unsigned)c < (unsigned)n) atomicAdd(&deg[c], 1);
    }
}

// --- parallel exclusive scan of deg -> rowptr/cursor (3 phases) ---
__global__ __launch_bounds__(TPB) void scan_part1(const int* __restrict__ deg,
                                                  int* __restrict__ bsum, int n) {
    int t0 = blockIdx.x * STILE + threadIdx.x * SI;
    int s = 0;
#pragma unroll
    for (int j = 0; j < SI; j++) { int i = t0 + j; if (i < n) s += deg[i]; }
#pragma unroll
    for (int off = 32; off >= 1; off >>= 1) s += __shfl_xor(s, off);
    __shared__ int ws[TPB / 64];
    if ((threadIdx.x & 63) == 0) ws[threadIdx.x >> 6] = s;
    __syncthreads();
    if (threadIdx.x == 0) {
        int tot = 0;
        for (int i = 0; i < TPB / 64; i++) tot += ws[i];
        bsum[blockIdx.x] = tot;
    }
}

__global__ void scan_part2(int* __restrict__ bsum, int nb,
                           int* __restrict__ rowptr, int n) {
    __shared__ int sums[1024];
    int tid = threadIdx.x;
    int v = (tid < nb) ? bsum[tid] : 0;
    sums[tid] = v;
    __syncthreads();
    for (int off = 1; off < 1024; off <<= 1) {
        int t = (tid >= off) ? sums[tid - off] : 0;
        __syncthreads();
        sums[tid] += t;
        __syncthreads();
    }
    if (tid < nb) bsum[tid] = (tid == 0) ? 0 : sums[tid - 1];
    if (tid == 0) rowptr[n] = sums[1023];
}

// also computes dinv[i] = rsqrt(deg[i]+1) (fused; saves a dispatch)
__global__ __launch_bounds__(TPB) void scan_part3(const int* __restrict__ deg,
                                                  const int* __restrict__ bsum,
                                                  int* __restrict__ rowptr,
                                                  int* __restrict__ cursor,
                                                  float* __restrict__ dinv, int n) {
    int tid = threadIdx.x;
    int lane = tid & 63, wv = tid >> 6;
    int t0 = blockIdx.x * STILE + tid * SI;
    int v[SI]; int s = 0;
#pragma unroll
    for (int j = 0; j < SI; j++) { int i = t0 + j; v[j] = (i < n) ? deg[i] : 0; s += v[j]; }
    int sc = s;  // inclusive wave scan
#pragma unroll
    for (int off = 1; off < 64; off <<= 1) {
        int t = __shfl_up(sc, off);
        if (lane >= off) sc += t;
    }
    __shared__ int wtot[TPB / 64];
    if (lane == 63) wtot[wv] = sc;
    __syncthreads();
    int woff = 0;
    for (int i = 0; i < wv; i++) woff += wtot[i];
    int off0 = bsum[blockIdx.x] + woff + (sc - s);
#pragma unroll
    for (int j = 0; j < SI; j++) {
        int i = t0 + j;
        if (i < n) {
            rowptr[i] = off0; cursor[i] = off0;
            dinv[i] = 1.0f / sqrtf((float)(v[j] + 1));  // +1 self-loop
        }
        off0 += v[j];
    }
}

// fill CSR with packed (src, dinv[src]) per edge
__global__ void fill_csr_kernel(const int* __restrict__ row, const int* __restrict__ col,
                                const float* __restrict__ dinv,
                                int* __restrict__ cursor, int2* __restrict__ es,
                                int E, int n) {
    int e = blockIdx.x * blockDim.x + threadIdx.x;
    if (e < E) {
        int c = col[e];
        if ((unsigned)c < (unsigned)n) {
            int r = row[e];
            int pos = atomicAdd(&cursor[c], 1);
            if ((unsigned)pos < (unsigned)E) {
                es[pos] = make_int2(r, __float_as_int(dinv[r]));
            }
        }
    }
}

// weight prep: W[K x M] fp32 -> Wt[M x K] bf16
__global__ void convert_wt_kernel(const float* __restrict__ W, unsigned short* __restrict__ Wt,
                                  int K, int M) {
    int idx = blockIdx.x * blockDim.x + threadIdx.x;
    if (idx < K * M) {
        int k = idx / M, m = idx % M;
        Wt[(size_t)m * K + k] = f2b(W[idx]);
    }
}

// ----------------------------- aggregation --------------------------------

template <int VEC> struct Pack;
template <> struct Pack<1> { using T = unsigned short; };
template <> struct Pack<2> { using T = unsigned int; };
template <> struct Pack<4> { using T = uint2; };

// One wave per node; lane owns VEC contiguous bf16 features inside a column
// window starting at wb; full row stride is d. Edge (src,dinv) batch-loaded
// 64-at-a-time (8B coalesced), broadcast via shfl, gathers unrolled 8-wide.
template <int VEC>
__global__ __launch_bounds__(TPB) void agg_win_kernel(
        const unsigned short* __restrict__ x, unsigned short* __restrict__ out,
        const int* __restrict__ rowptr, const int2* __restrict__ es,
        const float* __restrict__ dinv, const float* __restrict__ bias,
        int n, int d, int wb, int relu) {
    using P = typename Pack<VEC>::T;
    int wid  = (blockIdx.x * blockDim.x + threadIdx.x) >> 6;
    int lane = threadIdx.x & 63;
    if (wid >= n) return;
    int start = rowptr[wid], end = rowptr[wid + 1];
    float acc[4][VEC];
#pragma unroll
    for (int g = 0; g < 4; g++)
#pragma unroll
        for (int j = 0; j < VEC; j++) acc[g][j] = 0.f;
    const int fo = wb + lane * VEC;
    union U { P v; unsigned short u[VEC]; };

    for (int base = start; base < end; base += 64) {
        int idx = base + lane;
        int clamped = (idx < end) ? idx : (end - 1);
        int2 ev = es[clamped];
        int   sv = ev.x;
        float dv = (idx < end) ? __int_as_float(ev.y) : 0.f;
        int cnt = end - base; if (cnt > 64) cnt = 64;
        int j = 0;
        for (; j + 8 <= cnt; j += 8) {
            int s[8]; float e[8]; U l[8];
#pragma unroll
            for (int q = 0; q < 8; q++) { s[q] = __shfl(sv, j + q); e[q] = __shfl(dv, j + q); }
#pragma unroll
            for (int q = 0; q < 8; q++) l[q].v = *(const P*)(x + (size_t)s[q] * d + fo);
#pragma unroll
            for (int q = 0; q < 8; q++)
#pragma unroll
                for (int t = 0; t < VEC; t++)
                    acc[q & 3][t] = fmaf(e[q], b2f(l[q].u[t]), acc[q & 3][t]);
        }
        for (; j < cnt; j++) {
            int   s0 = __shfl(sv, j);
            float e0 = __shfl(dv, j);
            U l0; l0.v = *(const P*)(x + (size_t)s0 * d + fo);
#pragma unroll
            for (int t = 0; t < VEC; t++) acc[0][t] = fmaf(e0, b2f(l0.u[t]), acc[0][t]);
        }
    }

    float di = dinv[wid];
    U ls; ls.v = *(const P*)(x + (size_t)wid * d + fo);
    U st;
#pragma unroll
    for (int j = 0; j < VEC; j++) {
        float a = (acc[0][j] + acc[1][j]) + (acc[2][j] + acc[3][j]);
        float v = di * (a + di * b2f(ls.u[j]));
        if (bias) v += bias[fo + j];
        if (relu) v = fmaxf(v, 0.f);
        st.u[j] = f2b(v);
    }
    *(P*)(out + (size_t)wid * d + fo) = st.v;
}

// Fused L6-agg(256-wide) + bias + relu + L7 GEMM (256->2): per-node dot
// against W7 in registers, butterfly-reduce, write 2 fp32. No 51MB roundtrip.
__global__ __launch_bounds__(TPB) void agg_dot2_kernel(
        const unsigned short* __restrict__ x,
        const int* __restrict__ rowptr, const int2* __restrict__ es,
        const float* __restrict__ dinv, const float* __restrict__ bias6,
        const float* __restrict__ W7, float* __restrict__ pre, int n) {
    int wid  = (blockIdx.x * blockDim.x + threadIdx.x) >> 6;
    int lane = threadIdx.x & 63;
    if (wid >= n) return;
    int start = rowptr[wid], end = rowptr[wid + 1];
    float acc[4][4];
#pragma unroll
    for (int g = 0; g < 4; g++)
#pragma unroll
        for (int j = 0; j < 4; j++) acc[g][j] = 0.f;
    const int fo = lane * 4;
    union U { uint2 v; unsigned short u[4]; };

    for (int base = start; base < end; base += 64) {
        int idx = base + lane;
        int clamped = (idx < end) ? idx : (end - 1);
        int2 ev = es[clamped];
        int   sv = ev.x;
        float dv = (idx < end) ? __int_as_float(ev.y) : 0.f;
        int cnt = end - base; if (cnt > 64) cnt = 64;
        int j = 0;
        for (; j + 8 <= cnt; j += 8) {
            int s[8]; float e[8]; U l[8];
#pragma unroll
            for (int q = 0; q < 8; q++) { s[q] = __shfl(sv, j + q); e[q] = __shfl(dv, j + q); }
#pragma unroll
            for (int q = 0; q < 8; q++) l[q].v = *(const uint2*)(x + (size_t)s[q] * 256 + fo);
#pragma unroll
            for (int q = 0; q < 8; q++)
#pragma unroll
                for (int t = 0; t < 4; t++)
                    acc[q & 3][t] = fmaf(e[q], b2f(l[q].u[t]), acc[q & 3][t]);
        }
        for (; j < cnt; j++) {
            int   s0 = __shfl(sv, j);
            float e0 = __shfl(dv, j);
            U l0; l0.v = *(const uint2*)(x + (size_t)s0 * 256 + fo);
#pragma unroll
            for (int t = 0; t < 4; t++) acc[0][t] = fmaf(e0, b2f(l0.u[t]), acc[0][t]);
        }
    }

    float di = dinv[wid];
    U ls; ls.v = *(const uint2*)(x + (size_t)wid * 256 + fo);
    float c0 = 0.f, c1 = 0.f;
#pragma unroll
    for (int j = 0; j < 4; j++) {
        float a = (acc[0][j] + acc[1][j]) + (acc[2][j] + acc[3][j]);
        float h = di * (a + di * b2f(ls.u[j])) + bias6[fo + j];
        h = fmaxf(h, 0.f);                       // L6 output (fp32, unrounded)
        c0 = fmaf(h, W7[(fo + j) * 2 + 0], c0);  // L7 dot
        c1 = fmaf(h, W7[(fo + j) * 2 + 1], c1);
    }
#pragma unroll
    for (int off = 32; off >= 1; off >>= 1) {
        c0 += __shfl_xor(c0, off);
        c1 += __shfl_xor(c1, off);
    }
    if (lane == 0) { pre[(size_t)wid * 2 + 0] = c0; pre[(size_t)wid * 2 + 1] = c1; }
}

// Fused: agg(64-wide) + [64x64 GEMM] + bias + relu -> bf16 (L1/L2).
// Wave per node; agg parked in wave-local LDS (no barrier: same-wave rw).
__global__ __launch_bounds__(TPB) void agg_gemm64_kernel(
        const unsigned short* __restrict__ x, unsigned short* __restrict__ out,
        const int* __restrict__ rowptr, const int2* __restrict__ es,
        const float* __restrict__ dinv, const float* __restrict__ W,
        const float* __restrict__ bias, int n) {
    __shared__ float Ws[64 * 64];
    __shared__ float aggs[TPB / 64][64];
    const int tid = threadIdx.x;
    for (int i = tid; i < 64 * 64; i += TPB) Ws[i] = W[i];
    __syncthreads();
    int wid  = (blockIdx.x * TPB + tid) >> 6;
    int lane = tid & 63;
    int wv   = tid >> 6;
    if (wid >= n) return;
    int start = rowptr[wid], end = rowptr[wid + 1];
    float acc0 = 0.f, acc1 = 0.f, acc2 = 0.f, acc3 = 0.f;
    for (int base = start; base < end; base += 64) {
        int idx = base + lane;
        int clamped = (idx < end) ? idx : (end - 1);
        int2 ev = es[clamped];
        int   sv = ev.x;
        float dv = (idx < end) ? __int_as_float(ev.y) : 0.f;
        int cnt = end - base; if (cnt > 64) cnt = 64;
        int j = 0;
        for (; j + 4 <= cnt; j += 4) {
            int   s0 = __shfl(sv, j),     s1 = __shfl(sv, j + 1);
            int   s2 = __shfl(sv, j + 2), s3 = __shfl(sv, j + 3);
            float e0 = __shfl(dv, j),     e1 = __shfl(dv, j + 1);
            float e2 = __shfl(dv, j + 2), e3 = __shfl(dv, j + 3);
            acc0 = fmaf(e0, b2f(x[(size_t)s0 * 64 + lane]), acc0);
            acc1 = fmaf(e1, b2f(x[(size_t)s1 * 64 + lane]), acc1);
            acc2 = fmaf(e2, b2f(x[(size_t)s2 * 64 + lane]), acc2);
            acc3 = fmaf(e3, b2f(x[(size_t)s3 * 64 + lane]), acc3);
        }
        for (; j < cnt; j++) {
            int   s0 = __shfl(sv, j);
            float e0 = __shfl(dv, j);
            acc0 = fmaf(e0, b2f(x[(size_t)s0 * 64 + lane]), acc0);
        }
    }
    float di = dinv[wid];
    float a = di * (((acc0 + acc1) + (acc2 + acc3)) + di * b2f(x[(size_t)wid * 64 + lane]));
    aggs[wv][lane] = a;
    // same-wave LDS write->read: lockstep + compiler lgkmcnt, no barrier
    float v = bias[lane];
#pragma unroll 8
    for (int j = 0; j < 64; j++) v = fmaf(aggs[wv][j], Ws[j * 64 + lane], v);
    v = fmaxf(v, 0.f);
    out[(size_t)wid * 64 + lane] = f2b(v);
}

// Wave-per-node, edge-parallel aggregation for tiny dims (fp32 x), with
// optional fused (D -> 64) GEMM + bias + relu -> bf16 output (L0 path).
template <int D, int FUSE64>
__global__ __launch_bounds__(TPB) void agg_small_wave_kernel(
        const float* __restrict__ x, float* __restrict__ outf,
        unsigned short* __restrict__ outb,
        const int* __restrict__ rowptr, const int2* __restrict__ es,
        const float* __restrict__ dinv, const float* __restrict__ bias,
        const float* __restrict__ W, int n, int relu) {
    int wid  = (blockIdx.x * blockDim.x + threadIdx.x) >> 6;
    int lane = threadIdx.x & 63;
    if (wid >= n) return;
    int start = rowptr[wid], end = rowptr[wid + 1];
    float acc[D];
#pragma unroll
    for (int j = 0; j < D; j++) acc[j] = 0.f;
    for (int e = start + lane; e < end; e += 64) {
        int2 ev = es[e];
        int s = ev.x;
        float ds = __int_as_float(ev.y);
#pragma unroll
        for (int j = 0; j < D; j++) acc[j] = fmaf(ds, x[(size_t)s * D + j], acc[j]);
    }
#pragma unroll
    for (int j = 0; j < D; j++) {
#pragma unroll
        for (int off = 32; off >= 1; off >>= 1) acc[j] += __shfl_xor(acc[j], off);
    }
    float di = dinv[wid];
    float aggv[D];
#pragma unroll
    for (int j = 0; j < D; j++) aggv[j] = di * (acc[j] + di * x[(size_t)wid * D + j]);

    if (FUSE64) {
        float v = bias[lane];
#pragma unroll
        for (int j = 0; j < D; j++) v = fmaf(aggv[j], W[j * 64 + lane], v);
        v = fmaxf(v, 0.f);
        outb[(size_t)wid * 64 + lane] = f2b(v);
    } else {
        if (lane < D) {
            float v = aggv[lane];
            if (bias) v += bias[lane];
            if (relu) v = fmaxf(v, 0.f);
            outf[(size_t)wid * D + lane] = v;
        }
    }
}

// ------------------------------ MFMA GEMM ---------------------------------
// C[nr x M] = A[nr x K](bf16) * Wt[M x K](bf16, pre-transposed) (+bias)(+relu)
// 128x128 tile, BK=32, 2x2 waves x 4x4 frags of v_mfma_f32_16x16x32_bf16.
// Both A and B staged via global_load_lds (r8 A/B: B-direct-from-global
// measured ~+150us slower than LDS staging despite bank conflicts).
__global__ __launch_bounds__(256) void gemm_mfma_kernel(
        const unsigned short* __restrict__ A, const unsigned short* __restrict__ Wt,
        const float* __restrict__ bias, unsigned short* __restrict__ C,
        int nr, int K, int M, int relu, int addbias) {
    __shared__ alignas(16) short As[128 * 32];
    __shared__ alignas(16) short Bs[128 * 32];
    const int tid  = threadIdx.x;
    const int w    = tid >> 6;
    const int lane = tid & 63;
    const int wr   = w >> 1;
    const int wc   = w & 1;
    const int row0 = blockIdx.x * 128;
    const int col0 = blockIdx.y * 128;

    f32x4 acc[4][4];
#pragma unroll
    for (int i = 0; i < 4; i++)
#pragma unroll
        for (int j = 0; j < 4; j++) acc[i][j] = {0.f, 0.f, 0.f, 0.f};

    const int lrow   = lane >> 2;
    const int lcolB  = (lane & 3) * 16;
    const int fm     = lane & 15;
    const int fq     = lane >> 4;

    for (int kk = 0; kk < K; kk += 32) {
#pragma unroll
        for (int i = 0; i < 2; i++) {
            int r = w * 32 + i * 16 + lrow;
            int grow = row0 + r;
            const char* g = (const char*)A + ((size_t)grow * K + kk) * 2 + lcolB;
            short* lds = &As[(w * 32 + i * 16) * 32];
            if (grow < nr) async_copy16(lds, g);
        }
#pragma unroll
        for (int i = 0; i < 2; i++) {
            int r = w * 32 + i * 16 + lrow;
            int gcol = col0 + r;
            const char* g = (const char*)Wt + ((size_t)gcol * K + kk) * 2 + lcolB;
            short* lds = &Bs[(w * 32 + i * 16) * 32];
            async_copy16(lds, g);
        }
        __syncthreads();

        short8 a[4], b[4];
#pragma unroll
        for (int i = 0; i < 4; i++) {
            a[i] = *(const short8*)&As[(wr * 64 + i * 16 + fm) * 32 + fq * 8];
            b[i] = *(const short8*)&Bs[(wc * 64 + i * 16 + fm) * 32 + fq * 8];
        }
#pragma unroll
        for (int mi = 0; mi < 4; mi++)
#pragma unroll
            for (int ni = 0; ni < 4; ni++)
                acc[mi][ni] = __builtin_amdgcn_mfma_f32_16x16x32_bf16(
                    a[mi], b[ni], acc[mi][ni], 0, 0, 0);
        __syncthreads();
    }

#pragma unroll
    for (int mi = 0; mi < 4; mi++) {
#pragma unroll
        for (int r = 0; r < 4; r++) {
            int row = row0 + wr * 64 + mi * 16 + fq * 4 + r;
            if (row >= nr) continue;
            size_t rb = (size_t)row * M;
#pragma unroll
            for (int ni = 0; ni < 4; ni++) {
                int col = col0 + wc * 64 + ni * 16 + fm;
                float v = acc[mi][ni][r];
                if (addbias) v += bias[col];
                if (relu) v = fmaxf(v, 0.f);
                C[rb + col] = f2b(v);
            }
        }
    }
}

static inline void launch_gemm_mfma(const unsigned short* A, const unsigned short* Wt,
                                    const float* bias, unsigned short* C,
                                    int nr, int K, int M, int relu, int addbias,
                                    hipStream_t stream) {
    dim3 grid((nr + 127) / 128, M / 128);
    gemm_mfma_kernel<<<grid, 256, 0, stream>>>(A, Wt, bias, C, nr, K, M, relu, addbias);
}

// ------------------------------- driver -----------------------------------

static inline size_t al256(size_t x) { return (x + 255) & ~(size_t)255; }

extern "C" void kernel_launch(void* const* d_in, const int* in_sizes, int n_in,
                              void* d_out, int out_size, void* d_ws, size_t ws_size,
                              hipStream_t stream) {
    const float* x  = (const float*)d_in[0];
    const int*   ei = (const int*)d_in[1];
    const int E = in_sizes[1] / 2;
    const int n = in_sizes[0] / 3;
    const int* rowv = ei;        // sources
    const int* colv = ei + E;    // targets

    const float* Wf[8]; const float* bt[8];
    for (int i = 0; i < 8; i++) { Wf[i] = (const float*)d_in[2 + 2 * i]; bt[i] = (const float*)d_in[3 + 2 * i]; }

    char* p = (char*)d_ws;
    size_t used = 0;
    auto carve = [&](size_t bytes) -> char* {
        char* r = p + used; used += al256(bytes); return r;
    };
    int*   deg    = (int*)carve((size_t)n * 4);
    float* dinv   = (float*)carve((size_t)n * 4);
    int*   rowptr = (int*)carve((size_t)(n + 1) * 4);
    int*   cursor = (int*)carve((size_t)(n + 1) * 4);
    int*   bsum   = (int*)carve(4096 * 4);
    int2*  es     = (int2*)carve((size_t)E * 8);   // packed (src, dinv[src])
    unsigned short* bufA = (unsigned short*)carve((size_t)n * 512 * 2);
    unsigned short* bufB = (unsigned short*)carve((size_t)n * 512 * 2);
    const size_t wt3e = 64 * 128, wt4e = 128 * 1024, wt5e = 1024 * 512, wt6e = 512 * 256;
    unsigned short* wt3 = (unsigned short*)carve((wt3e + wt4e + wt5e + wt6e) * 2);
    unsigned short* wt4 = wt3 + wt3e;
    unsigned short* wt5 = wt4 + wt4e;
    unsigned short* wt6 = wt5 + wt5e;
    size_t avail = (ws_size > used) ? (ws_size - used) : 0;
    int chunk = (int)(avail / (1024 * 2));
    if (chunk > n) chunk = n;
    chunk &= ~127;                  // multiple of 128 for clean MFMA tiles
    if (chunk < 2048) chunk = 2048; // floor
    char* tmp_raw = carve((size_t)chunk * 1024 * 2);
    unsigned short* tmpb = (unsigned short*)tmp_raw;
    float* tmpf = (float*)tmp_raw;   // reused: n x 2 fp32 (L7 pre-agg)

    const int EB = (E + TPB - 1) / TPB;
    const int NW = (n + 3) / 4;      // wave-per-node kernels, 4 waves/block
    const int SBK = (n + STILE - 1) / STILE;  // scan blocks

    // ---- graph preprocessing ----
    hipMemsetAsync(deg, 0, (size_t)n * 4, stream);
    count_deg_kernel<<<EB, TPB, 0, stream>>>(colv, deg, E, n);
    scan_part1<<<SBK, TPB, 0, stream>>>(deg, bsum, n);
    scan_part2<<<1, 1024, 0, stream>>>(bsum, SBK, rowptr, n);
    scan_part3<<<SBK, TPB, 0, stream>>>(deg, bsum, rowptr, cursor, dinv, n);
    fill_csr_kernel<<<EB, TPB, 0, stream>>>(rowv, colv, dinv, cursor, es, E, n);

    // ---- weight prep ----
    convert_wt_kernel<<<(int)((wt3e + 255) / 256), 256, 0, stream>>>(Wf[3], wt3, 64, 128);
    convert_wt_kernel<<<(int)((wt4e + 255) / 256), 256, 0, stream>>>(Wf[4], wt4, 128, 1024);
    convert_wt_kernel<<<(int)((wt5e + 255) / 256), 256, 0, stream>>>(Wf[5], wt5, 1024, 512);
    convert_wt_kernel<<<(int)((wt6e + 255) / 256), 256, 0, stream>>>(Wf[6], wt6, 512, 256);

    // ---- L0: fused agg(d=3) + (3->64 GEMM) + bias + relu -> bf16 ----
    agg_small_wave_kernel<3, 1><<<NW, TPB, 0, stream>>>(
        x, nullptr, bufA, rowptr, es, dinv, bt[0], Wf[0], n, 1);

    // ---- L1, L2: fused agg + 64x64 GEMM + bias + relu ----
    agg_gemm64_kernel<<<NW, TPB, 0, stream>>>(bufA, bufB, rowptr, es, dinv, Wf[1], bt[1], n);
    agg_gemm64_kernel<<<NW, TPB, 0, stream>>>(bufB, bufA, rowptr, es, dinv, Wf[2], bt[2], n);

    // ---- L3: 64 -> 128 (agg-first, MFMA) ----
    agg_win_kernel<1><<<NW, TPB, 0, stream>>>(bufA, bufB, rowptr, es, dinv, nullptr, n, 64, 0, 0);
    launch_gemm_mfma(bufB, wt3, bt[3], bufA, n, 64, 128, 1, 1, stream);

    // ---- L4+L5 fused: agg on 128, then chunked (relu(.@W4+b4)) @ W5 ----
    agg_win_kernel<2><<<NW, TPB, 0, stream>>>(bufA, bufB, rowptr, es, dinv, nullptr, n, 128, 0, 0);
    for (int r0 = 0; r0 < n; r0 += chunk) {
        int ch = n - r0; if (ch > chunk) ch = chunk;
        launch_gemm_mfma(bufB + (size_t)r0 * 128, wt4, bt[4], tmpb, ch, 128, 1024, 1, 1, stream);
        launch_gemm_mfma(tmpb, wt5, nullptr, bufA + (size_t)r0 * 512, ch, 1024, 512, 0, 0, stream);
    }
    // L5 epilogue: agg on 512 in TWO 256-wide passes (r7: 4x128 measured worse)
    agg_win_kernel<4><<<NW, TPB, 0, stream>>>(bufA, bufB, rowptr, es, dinv, bt[5], n, 512, 0, 1);
    agg_win_kernel<4><<<NW, TPB, 0, stream>>>(bufA, bufB, rowptr, es, dinv, bt[5], n, 512, 256, 1);

    // ---- L6: 512 -> 256 (MFMA), then fused agg(256)+bias+relu+L7 dot -> pre ----
    launch_gemm_mfma(bufB, wt6, nullptr, bufA, n, 512, 256, 0, 0, stream);
    agg_dot2_kernel<<<NW, TPB, 0, stream>>>(bufA, rowptr, es, dinv, bt[6], Wf[7], tmpf, n);

    // ---- L7 epilogue: agg d=2 + bias, no relu -> d_out ----
    agg_small_wave_kernel<2, 0><<<NW, TPB, 0, stream>>>(
        tmpf, (float*)d_out, nullptr, rowptr, es, dinv, bt[7], nullptr, n, 0);
}

// Round 10
// 1969.910 us; speedup vs baseline: 1.1231x; 1.0197x over previous
//
#include <hip/hip_runtime.h>
#include <hip/hip_bf16.h>
#include <cstdint>
#include <cstddef>

// ---------------------------------------------------------------------------
// GCNemb: 8-layer GCN. N=100000, E=3200000.
//   - CSR by target; agg(xW)==agg(x)W -> aggregate on smaller side.
//   - bf16 activation storage, fp32 arithmetic (absmax 3.05e-5 vs 6.56e-5 thr).
//   - Gather plateau (measured r4-r9): wide agg passes pin at ~3.87 TB/s HBM
//     + ~4.2 TB/s cache (~8 TB/s effective); invariant to unroll depth,
//     window width (128/256/512), edge packing. Structural.
//   - GEMM B-path: LDS staging (r6<->r8 A/B: B-direct from global +150us).
//   - r10: L4/L5 fusion chunk enlarged by reusing bufB slack (chunk 11k->37k,
//     18->6 GEMM dispatches, L5 GEMM 348->~1170 blocks).
// ---------------------------------------------------------------------------

#define TPB 256
#define SI 8                 // scan items per thread
#define STILE (TPB * SI)     // 2048 elements per scan block

typedef short short8 __attribute__((ext_vector_type(8)));
typedef float f32x4 __attribute__((ext_vector_type(4)));

__device__ __forceinline__ float b2f(unsigned short u) {
    union { unsigned int i; float f; } c; c.i = ((unsigned int)u) << 16; return c.f;
}
__device__ __forceinline__ unsigned short f2b(float f) {
    __hip_bfloat16 h = __float2bfloat16(f);
    union { __hip_bfloat16 h; unsigned short u; } c; c.h = h; return c.u;
}

__device__ __forceinline__ void async_copy16(void* lds, const void* g) {
    __builtin_amdgcn_global_load_lds(
        (const __attribute__((address_space(1))) void*)g,
        (__attribute__((address_space(3))) void*)lds,
        16, 0, 0);
}

// ------------------------------ graph prep --------------------------------

__global__ void count_deg_kernel(const int* __restrict__ col, int* __restrict__ deg,
                                 int E, int n) {
    int e = blockIdx.x * blockDim.x + threadIdx.x;
    if (e < E) {
        int c = col[e];
        if ((unsigned)c < (unsigned)n) atomicAdd(&deg[c], 1);
    }
}

// --- parallel exclusive scan of deg -> rowptr/cursor (3 phases) ---
__global__ __launch_bounds__(TPB) void scan_part1(const int* __restrict__ deg,
                                                  int* __restrict__ bsum, int n) {
    int t0 = blockIdx.x * STILE + threadIdx.x * SI;
    int s = 0;
#pragma unroll
    for (int j = 0; j < SI; j++) { int i = t0 + j; if (i < n) s += deg[i]; }
#pragma unroll
    for (int off = 32; off >= 1; off >>= 1) s += __shfl_xor(s, off);
    __shared__ int ws[TPB / 64];
    if ((threadIdx.x & 63) == 0) ws[threadIdx.x >> 6] = s;
    __syncthreads();
    if (threadIdx.x == 0) {
        int tot = 0;
        for (int i = 0; i < TPB / 64; i++) tot += ws[i];
        bsum[blockIdx.x] = tot;
    }
}

__global__ void scan_part2(int* __restrict__ bsum, int nb,
                           int* __restrict__ rowptr, int n) {
    __shared__ int sums[1024];
    int tid = threadIdx.x;
    int v = (tid < nb) ? bsum[tid] : 0;
    sums[tid] = v;
    __syncthreads();
    for (int off = 1; off < 1024; off <<= 1) {
        int t = (tid >= off) ? sums[tid - off] : 0;
        __syncthreads();
        sums[tid] += t;
        __syncthreads();
    }
    if (tid < nb) bsum[tid] = (tid == 0) ? 0 : sums[tid - 1];
    if (tid == 0) rowptr[n] = sums[1023];
}

// also computes dinv[i] = rsqrt(deg[i]+1) (fused; saves a dispatch)
__global__ __launch_bounds__(TPB) void scan_part3(const int* __restrict__ deg,
                                                  const int* __restrict__ bsum,
                                                  int* __restrict__ rowptr,
                                                  int* __restrict__ cursor,
                                                  float* __restrict__ dinv, int n) {
    int tid = threadIdx.x;
    int lane = tid & 63, wv = tid >> 6;
    int t0 = blockIdx.x * STILE + tid * SI;
    int v[SI]; int s = 0;
#pragma unroll
    for (int j = 0; j < SI; j++) { int i = t0 + j; v[j] = (i < n) ? deg[i] : 0; s += v[j]; }
    int sc = s;  // inclusive wave scan
#pragma unroll
    for (int off = 1; off < 64; off <<= 1) {
        int t = __shfl_up(sc, off);
        if (lane >= off) sc += t;
    }
    __shared__ int wtot[TPB / 64];
    if (lane == 63) wtot[wv] = sc;
    __syncthreads();
    int woff = 0;
    for (int i = 0; i < wv; i++) woff += wtot[i];
    int off0 = bsum[blockIdx.x] + woff + (sc - s);
#pragma unroll
    for (int j = 0; j < SI; j++) {
        int i = t0 + j;
        if (i < n) {
            rowptr[i] = off0; cursor[i] = off0;
            dinv[i] = 1.0f / sqrtf((float)(v[j] + 1));  // +1 self-loop
        }
        off0 += v[j];
    }
}

// fill CSR with packed (src, dinv[src]) per edge
__global__ void fill_csr_kernel(const int* __restrict__ row, const int* __restrict__ col,
                                const float* __restrict__ dinv,
                                int* __restrict__ cursor, int2* __restrict__ es,
                                int E, int n) {
    int e = blockIdx.x * blockDim.x + threadIdx.x;
    if (e < E) {
        int c = col[e];
        if ((unsigned)c < (unsigned)n) {
            int r = row[e];
            int pos = atomicAdd(&cursor[c], 1);
            if ((unsigned)pos < (unsigned)E) {
                es[pos] = make_int2(r, __float_as_int(dinv[r]));
            }
        }
    }
}

// weight prep: W[K x M] fp32 -> Wt[M x K] bf16
__global__ void convert_wt_kernel(const float* __restrict__ W, unsigned short* __restrict__ Wt,
                                  int K, int M) {
    int idx = blockIdx.x * blockDim.x + threadIdx.x;
    if (idx < K * M) {
        int k = idx / M, m = idx % M;
        Wt[(size_t)m * K + k] = f2b(W[idx]);
    }
}

// ----------------------------- aggregation --------------------------------

template <int VEC> struct Pack;
template <> struct Pack<1> { using T = unsigned short; };
template <> struct Pack<2> { using T = unsigned int; };
template <> struct Pack<4> { using T = uint2; };

// One wave per node; lane owns VEC contiguous bf16 features inside a column
// window starting at wb; full row stride is d. Edge (src,dinv) batch-loaded
// 64-at-a-time (8B coalesced), broadcast via shfl, gathers unrolled 8-wide.
template <int VEC>
__global__ __launch_bounds__(TPB) void agg_win_kernel(
        const unsigned short* __restrict__ x, unsigned short* __restrict__ out,
        const int* __restrict__ rowptr, const int2* __restrict__ es,
        const float* __restrict__ dinv, const float* __restrict__ bias,
        int n, int d, int wb, int relu) {
    using P = typename Pack<VEC>::T;
    int wid  = (blockIdx.x * blockDim.x + threadIdx.x) >> 6;
    int lane = threadIdx.x & 63;
    if (wid >= n) return;
    int start = rowptr[wid], end = rowptr[wid + 1];
    float acc[4][VEC];
#pragma unroll
    for (int g = 0; g < 4; g++)
#pragma unroll
        for (int j = 0; j < VEC; j++) acc[g][j] = 0.f;
    const int fo = wb + lane * VEC;
    union U { P v; unsigned short u[VEC]; };

    for (int base = start; base < end; base += 64) {
        int idx = base + lane;
        int clamped = (idx < end) ? idx : (end - 1);
        int2 ev = es[clamped];
        int   sv = ev.x;
        float dv = (idx < end) ? __int_as_float(ev.y) : 0.f;
        int cnt = end - base; if (cnt > 64) cnt = 64;
        int j = 0;
        for (; j + 8 <= cnt; j += 8) {
            int s[8]; float e[8]; U l[8];
#pragma unroll
            for (int q = 0; q < 8; q++) { s[q] = __shfl(sv, j + q); e[q] = __shfl(dv, j + q); }
#pragma unroll
            for (int q = 0; q < 8; q++) l[q].v = *(const P*)(x + (size_t)s[q] * d + fo);
#pragma unroll
            for (int q = 0; q < 8; q++)
#pragma unroll
                for (int t = 0; t < VEC; t++)
                    acc[q & 3][t] = fmaf(e[q], b2f(l[q].u[t]), acc[q & 3][t]);
        }
        for (; j < cnt; j++) {
            int   s0 = __shfl(sv, j);
            float e0 = __shfl(dv, j);
            U l0; l0.v = *(const P*)(x + (size_t)s0 * d + fo);
#pragma unroll
            for (int t = 0; t < VEC; t++) acc[0][t] = fmaf(e0, b2f(l0.u[t]), acc[0][t]);
        }
    }

    float di = dinv[wid];
    U ls; ls.v = *(const P*)(x + (size_t)wid * d + fo);
    U st;
#pragma unroll
    for (int j = 0; j < VEC; j++) {
        float a = (acc[0][j] + acc[1][j]) + (acc[2][j] + acc[3][j]);
        float v = di * (a + di * b2f(ls.u[j]));
        if (bias) v += bias[fo + j];
        if (relu) v = fmaxf(v, 0.f);
        st.u[j] = f2b(v);
    }
    *(P*)(out + (size_t)wid * d + fo) = st.v;
}

// Fused L6-agg(256-wide) + bias + relu + L7 GEMM (256->2): per-node dot
// against W7 in registers, butterfly-reduce, write 2 fp32. No 51MB roundtrip.
__global__ __launch_bounds__(TPB) void agg_dot2_kernel(
        const unsigned short* __restrict__ x,
        const int* __restrict__ rowptr, const int2* __restrict__ es,
        const float* __restrict__ dinv, const float* __restrict__ bias6,
        const float* __restrict__ W7, float* __restrict__ pre, int n) {
    int wid  = (blockIdx.x * blockDim.x + threadIdx.x) >> 6;
    int lane = threadIdx.x & 63;
    if (wid >= n) return;
    int start = rowptr[wid], end = rowptr[wid + 1];
    float acc[4][4];
#pragma unroll
    for (int g = 0; g < 4; g++)
#pragma unroll
        for (int j = 0; j < 4; j++) acc[g][j] = 0.f;
    const int fo = lane * 4;
    union U { uint2 v; unsigned short u[4]; };

    for (int base = start; base < end; base += 64) {
        int idx = base + lane;
        int clamped = (idx < end) ? idx : (end - 1);
        int2 ev = es[clamped];
        int   sv = ev.x;
        float dv = (idx < end) ? __int_as_float(ev.y) : 0.f;
        int cnt = end - base; if (cnt > 64) cnt = 64;
        int j = 0;
        for (; j + 8 <= cnt; j += 8) {
            int s[8]; float e[8]; U l[8];
#pragma unroll
            for (int q = 0; q < 8; q++) { s[q] = __shfl(sv, j + q); e[q] = __shfl(dv, j + q); }
#pragma unroll
            for (int q = 0; q < 8; q++) l[q].v = *(const uint2*)(x + (size_t)s[q] * 256 + fo);
#pragma unroll
            for (int q = 0; q < 8; q++)
#pragma unroll
                for (int t = 0; t < 4; t++)
                    acc[q & 3][t] = fmaf(e[q], b2f(l[q].u[t]), acc[q & 3][t]);
        }
        for (; j < cnt; j++) {
            int   s0 = __shfl(sv, j);
            float e0 = __shfl(dv, j);
            U l0; l0.v = *(const uint2*)(x + (size_t)s0 * 256 + fo);
#pragma unroll
            for (int t = 0; t < 4; t++) acc[0][t] = fmaf(e0, b2f(l0.u[t]), acc[0][t]);
        }
    }

    float di = dinv[wid];
    U ls; ls.v = *(const uint2*)(x + (size_t)wid * 256 + fo);
    float c0 = 0.f, c1 = 0.f;
#pragma unroll
    for (int j = 0; j < 4; j++) {
        float a = (acc[0][j] + acc[1][j]) + (acc[2][j] + acc[3][j]);
        float h = di * (a + di * b2f(ls.u[j])) + bias6[fo + j];
        h = fmaxf(h, 0.f);                       // L6 output (fp32, unrounded)
        c0 = fmaf(h, W7[(fo + j) * 2 + 0], c0);  // L7 dot
        c1 = fmaf(h, W7[(fo + j) * 2 + 1], c1);
    }
#pragma unroll
    for (int off = 32; off >= 1; off >>= 1) {
        c0 += __shfl_xor(c0, off);
        c1 += __shfl_xor(c1, off);
    }
    if (lane == 0) { pre[(size_t)wid * 2 + 0] = c0; pre[(size_t)wid * 2 + 1] = c1; }
}

// Fused: agg(64-wide) + [64x64 GEMM] + bias + relu -> bf16 (L1/L2).
// Wave per node; agg parked in wave-local LDS (no barrier: same-wave rw).
__global__ __launch_bounds__(TPB) void agg_gemm64_kernel(
        const unsigned short* __restrict__ x, unsigned short* __restrict__ out,
        const int* __restrict__ rowptr, const int2* __restrict__ es,
        const float* __restrict__ dinv, const float* __restrict__ W,
        const float* __restrict__ bias, int n) {
    __shared__ float Ws[64 * 64];
    __shared__ float aggs[TPB / 64][64];
    const int tid = threadIdx.x;
    for (int i = tid; i < 64 * 64; i += TPB) Ws[i] = W[i];
    __syncthreads();
    int wid  = (blockIdx.x * TPB + tid) >> 6;
    int lane = tid & 63;
    int wv   = tid >> 6;
    if (wid >= n) return;
    int start = rowptr[wid], end = rowptr[wid + 1];
    float acc0 = 0.f, acc1 = 0.f, acc2 = 0.f, acc3 = 0.f;
    for (int base = start; base < end; base += 64) {
        int idx = base + lane;
        int clamped = (idx < end) ? idx : (end - 1);
        int2 ev = es[clamped];
        int   sv = ev.x;
        float dv = (idx < end) ? __int_as_float(ev.y) : 0.f;
        int cnt = end - base; if (cnt > 64) cnt = 64;
        int j = 0;
        for (; j + 4 <= cnt; j += 4) {
            int   s0 = __shfl(sv, j),     s1 = __shfl(sv, j + 1);
            int   s2 = __shfl(sv, j + 2), s3 = __shfl(sv, j + 3);
            float e0 = __shfl(dv, j),     e1 = __shfl(dv, j + 1);
            float e2 = __shfl(dv, j + 2), e3 = __shfl(dv, j + 3);
            acc0 = fmaf(e0, b2f(x[(size_t)s0 * 64 + lane]), acc0);
            acc1 = fmaf(e1, b2f(x[(size_t)s1 * 64 + lane]), acc1);
            acc2 = fmaf(e2, b2f(x[(size_t)s2 * 64 + lane]), acc2);
            acc3 = fmaf(e3, b2f(x[(size_t)s3 * 64 + lane]), acc3);
        }
        for (; j < cnt; j++) {
            int   s0 = __shfl(sv, j);
            float e0 = __shfl(dv, j);
            acc0 = fmaf(e0, b2f(x[(size_t)s0 * 64 + lane]), acc0);
        }
    }
    float di = dinv[wid];
    float a = di * (((acc0 + acc1) + (acc2 + acc3)) + di * b2f(x[(size_t)wid * 64 + lane]));
    aggs[wv][lane] = a;
    // same-wave LDS write->read: lockstep + compiler lgkmcnt, no barrier
    float v = bias[lane];
#pragma unroll 8
    for (int j = 0; j < 64; j++) v = fmaf(aggs[wv][j], Ws[j * 64 + lane], v);
    v = fmaxf(v, 0.f);
    out[(size_t)wid * 64 + lane] = f2b(v);
}

// Wave-per-node, edge-parallel aggregation for tiny dims (fp32 x), with
// optional fused (D -> 64) GEMM + bias + relu -> bf16 output (L0 path).
template <int D, int FUSE64>
__global__ __launch_bounds__(TPB) void agg_small_wave_kernel(
        const float* __restrict__ x, float* __restrict__ outf,
        unsigned short* __restrict__ outb,
        const int* __restrict__ rowptr, const int2* __restrict__ es,
        const float* __restrict__ dinv, const float* __restrict__ bias,
        const float* __restrict__ W, int n, int relu) {
    int wid  = (blockIdx.x * blockDim.x + threadIdx.x) >> 6;
    int lane = threadIdx.x & 63;
    if (wid >= n) return;
    int start = rowptr[wid], end = rowptr[wid + 1];
    float acc[D];
#pragma unroll
    for (int j = 0; j < D; j++) acc[j] = 0.f;
    for (int e = start + lane; e < end; e += 64) {
        int2 ev = es[e];
        int s = ev.x;
        float ds = __int_as_float(ev.y);
#pragma unroll
        for (int j = 0; j < D; j++) acc[j] = fmaf(ds, x[(size_t)s * D + j], acc[j]);
    }
#pragma unroll
    for (int j = 0; j < D; j++) {
#pragma unroll
        for (int off = 32; off >= 1; off >>= 1) acc[j] += __shfl_xor(acc[j], off);
    }
    float di = dinv[wid];
    float aggv[D];
#pragma unroll
    for (int j = 0; j < D; j++) aggv[j] = di * (acc[j] + di * x[(size_t)wid * D + j]);

    if (FUSE64) {
        float v = bias[lane];
#pragma unroll
        for (int j = 0; j < D; j++) v = fmaf(aggv[j], W[j * 64 + lane], v);
        v = fmaxf(v, 0.f);
        outb[(size_t)wid * 64 + lane] = f2b(v);
    } else {
        if (lane < D) {
            float v = aggv[lane];
            if (bias) v += bias[lane];
            if (relu) v = fmaxf(v, 0.f);
            outf[(size_t)wid * D + lane] = v;
        }
    }
}

// ------------------------------ MFMA GEMM ---------------------------------
// C[nr x M] = A[nr x K](bf16) * Wt[M x K](bf16, pre-transposed) (+bias)(+relu)
// 128x128 tile, BK=32, 2x2 waves x 4x4 frags of v_mfma_f32_16x16x32_bf16.
// Both A and B staged via global_load_lds (r8 A/B: B-direct-from-global
// measured ~+150us slower than LDS staging despite bank conflicts).
__global__ __launch_bounds__(256) void gemm_mfma_kernel(
        const unsigned short* __restrict__ A, const unsigned short* __restrict__ Wt,
        const float* __restrict__ bias, unsigned short* __restrict__ C,
        int nr, int K, int M, int relu, int addbias) {
    __shared__ alignas(16) short As[128 * 32];
    __shared__ alignas(16) short Bs[128 * 32];
    const int tid  = threadIdx.x;
    const int w    = tid >> 6;
    const int lane = tid & 63;
    const int wr   = w >> 1;
    const int wc   = w & 1;
    const int row0 = blockIdx.x * 128;
    const int col0 = blockIdx.y * 128;

    f32x4 acc[4][4];
#pragma unroll
    for (int i = 0; i < 4; i++)
#pragma unroll
        for (int j = 0; j < 4; j++) acc[i][j] = {0.f, 0.f, 0.f, 0.f};

    const int lrow   = lane >> 2;
    const int lcolB  = (lane & 3) * 16;
    const int fm     = lane & 15;
    const int fq     = lane >> 4;

    for (int kk = 0; kk < K; kk += 32) {
#pragma unroll
        for (int i = 0; i < 2; i++) {
            int r = w * 32 + i * 16 + lrow;
            int grow = row0 + r;
            const char* g = (const char*)A + ((size_t)grow * K + kk) * 2 + lcolB;
            short* lds = &As[(w * 32 + i * 16) * 32];
            if (grow < nr) async_copy16(lds, g);
        }
#pragma unroll
        for (int i = 0; i < 2; i++) {
            int r = w * 32 + i * 16 + lrow;
            int gcol = col0 + r;
            const char* g = (const char*)Wt + ((size_t)gcol * K + kk) * 2 + lcolB;
            short* lds = &Bs[(w * 32 + i * 16) * 32];
            async_copy16(lds, g);
        }
        __syncthreads();

        short8 a[4], b[4];
#pragma unroll
        for (int i = 0; i < 4; i++) {
            a[i] = *(const short8*)&As[(wr * 64 + i * 16 + fm) * 32 + fq * 8];
            b[i] = *(const short8*)&Bs[(wc * 64 + i * 16 + fm) * 32 + fq * 8];
        }
#pragma unroll
        for (int mi = 0; mi < 4; mi++)
#pragma unroll
            for (int ni = 0; ni < 4; ni++)
                acc[mi][ni] = __builtin_amdgcn_mfma_f32_16x16x32_bf16(
                    a[mi], b[ni], acc[mi][ni], 0, 0, 0);
        __syncthreads();
    }

#pragma unroll
    for (int mi = 0; mi < 4; mi++) {
#pragma unroll
        for (int r = 0; r < 4; r++) {
            int row = row0 + wr * 64 + mi * 16 + fq * 4 + r;
            if (row >= nr) continue;
            size_t rb = (size_t)row * M;
#pragma unroll
            for (int ni = 0; ni < 4; ni++) {
                int col = col0 + wc * 64 + ni * 16 + fm;
                float v = acc[mi][ni][r];
                if (addbias) v += bias[col];
                if (relu) v = fmaxf(v, 0.f);
                C[rb + col] = f2b(v);
            }
        }
    }
}

static inline void launch_gemm_mfma(const unsigned short* A, const unsigned short* Wt,
                                    const float* bias, unsigned short* C,
                                    int nr, int K, int M, int relu, int addbias,
                                    hipStream_t stream) {
    dim3 grid((nr + 127) / 128, M / 128);
    gemm_mfma_kernel<<<grid, 256, 0, stream>>>(A, Wt, bias, C, nr, K, M, relu, addbias);
}

// ------------------------------- driver -----------------------------------

static inline size_t al256(size_t x) { return (x + 255) & ~(size_t)255; }

extern "C" void kernel_launch(void* const* d_in, const int* in_sizes, int n_in,
                              void* d_out, int out_size, void* d_ws, size_t ws_size,
                              hipStream_t stream) {
    const float* x  = (const float*)d_in[0];
    const int*   ei = (const int*)d_in[1];
    const int E = in_sizes[1] / 2;
    const int n = in_sizes[0] / 3;
    const int* rowv = ei;        // sources
    const int* colv = ei + E;    // targets

    const float* Wf[8]; const float* bt[8];
    for (int i = 0; i < 8; i++) { Wf[i] = (const float*)d_in[2 + 2 * i]; bt[i] = (const float*)d_in[3 + 2 * i]; }

    char* p = (char*)d_ws;
    size_t used = 0;
    auto carve = [&](size_t bytes) -> char* {
        char* r = p + used; used += al256(bytes); return r;
    };
    int*   deg    = (int*)carve((size_t)n * 4);
    float* dinv   = (float*)carve((size_t)n * 4);
    int*   rowptr = (int*)carve((size_t)(n + 1) * 4);
    int*   cursor = (int*)carve((size_t)(n + 1) * 4);
    int*   bsum   = (int*)carve(4096 * 4);
    int2*  es     = (int2*)carve((size_t)E * 8);   // packed (src, dinv[src])
    unsigned short* bufA = (unsigned short*)carve((size_t)n * 512 * 2);
    unsigned short* bufB = (unsigned short*)carve((size_t)n * 512 * 2);
    const size_t wt3e = 64 * 128, wt4e = 128 * 1024, wt5e = 1024 * 512, wt6e = 512 * 256;
    unsigned short* wt3 = (unsigned short*)carve((wt3e + wt4e + wt5e + wt6e) * 2);
    unsigned short* wt4 = wt3 + wt3e;
    unsigned short* wt5 = wt4 + wt4e;
    unsigned short* wt6 = wt5 + wt5e;
    float* tmpf = (float*)carve((size_t)n * 2 * 4);  // L7 pre-agg (n x 2 fp32)

    // L4/L5 chunk buffer lives in bufB's slack: during that phase bufB holds
    // only agg4 (n x 128 bf16); the remaining (512-128)*n*2 B is free.
    size_t agg4_elems = al256((size_t)n * 128 * 2) / 2;
    unsigned short* tmpb = bufB + agg4_elems;
    size_t slack_elems = (size_t)n * 512 - agg4_elems;
    int chunk = (int)(slack_elems / 1024);
    if (chunk > n) chunk = n;
    chunk &= ~127;                  // multiple of 128 for clean MFMA tiles
    if (chunk < 128) chunk = 128;

    const int EB = (E + TPB - 1) / TPB;
    const int NW = (n + 3) / 4;      // wave-per-node kernels, 4 waves/block
    const int SBK = (n + STILE - 1) / STILE;  // scan blocks

    // ---- graph preprocessing ----
    hipMemsetAsync(deg, 0, (size_t)n * 4, stream);
    count_deg_kernel<<<EB, TPB, 0, stream>>>(colv, deg, E, n);
    scan_part1<<<SBK, TPB, 0, stream>>>(deg, bsum, n);
    scan_part2<<<1, 1024, 0, stream>>>(bsum, SBK, rowptr, n);
    scan_part3<<<SBK, TPB, 0, stream>>>(deg, bsum, rowptr, cursor, dinv, n);
    fill_csr_kernel<<<EB, TPB, 0, stream>>>(rowv, colv, dinv, cursor, es, E, n);

    // ---- weight prep ----
    convert_wt_kernel<<<(int)((wt3e + 255) / 256), 256, 0, stream>>>(Wf[3], wt3, 64, 128);
    convert_wt_kernel<<<(int)((wt4e + 255) / 256), 256, 0, stream>>>(Wf[4], wt4, 128, 1024);
    convert_wt_kernel<<<(int)((wt5e + 255) / 256), 256, 0, stream>>>(Wf[5], wt5, 1024, 512);
    convert_wt_kernel<<<(int)((wt6e + 255) / 256), 256, 0, stream>>>(Wf[6], wt6, 512, 256);

    // ---- L0: fused agg(d=3) + (3->64 GEMM) + bias + relu -> bf16 ----
    agg_small_wave_kernel<3, 1><<<NW, TPB, 0, stream>>>(
        x, nullptr, bufA, rowptr, es, dinv, bt[0], Wf[0], n, 1);

    // ---- L1, L2: fused agg + 64x64 GEMM + bias + relu ----
    agg_gemm64_kernel<<<NW, TPB, 0, stream>>>(bufA, bufB, rowptr, es, dinv, Wf[1], bt[1], n);
    agg_gemm64_kernel<<<NW, TPB, 0, stream>>>(bufB, bufA, rowptr, es, dinv, Wf[2], bt[2], n);

    // ---- L3: 64 -> 128 (agg-first, MFMA) ----
    agg_win_kernel<1><<<NW, TPB, 0, stream>>>(bufA, bufB, rowptr, es, dinv, nullptr, n, 64, 0, 0);
    launch_gemm_mfma(bufB, wt3, bt[3], bufA, n, 64, 128, 1, 1, stream);

    // ---- L4+L5 fused: agg on 128 (front of bufB), then chunked
    //      (relu(.@W4+b4)) @ W5 with tmpb in bufB's slack ----
    agg_win_kernel<2><<<NW, TPB, 0, stream>>>(bufA, bufB, rowptr, es, dinv, nullptr, n, 128, 0, 0);
    for (int r0 = 0; r0 < n; r0 += chunk) {
        int ch = n - r0; if (ch > chunk) ch = chunk;
        launch_gemm_mfma(bufB + (size_t)r0 * 128, wt4, bt[4], tmpb, ch, 128, 1024, 1, 1, stream);
        launch_gemm_mfma(tmpb, wt5, nullptr, bufA + (size_t)r0 * 512, ch, 1024, 512, 0, 0, stream);
    }
    // L5 epilogue: agg on 512 in TWO 256-wide passes (r7: 4x128 measured worse)
    agg_win_kernel<4><<<NW, TPB, 0, stream>>>(bufA, bufB, rowptr, es, dinv, bt[5], n, 512, 0, 1);
    agg_win_kernel<4><<<NW, TPB, 0, stream>>>(bufA, bufB, rowptr, es, dinv, bt[5], n, 512, 256, 1);

    // ---- L6: 512 -> 256 (MFMA), then fused agg(256)+bias+relu+L7 dot -> pre ----
    launch_gemm_mfma(bufB, wt6, nullptr, bufA, n, 512, 256, 0, 0, stream);
    agg_dot2_kernel<<<NW, TPB, 0, stream>>>(bufA, rowptr, es, dinv, bt[6], Wf[7], tmpf, n);

    // ---- L7 epilogue: agg d=2 + bias, no relu -> d_out ----
    agg_small_wave_kernel<2, 0><<<NW, TPB, 0, stream>>>(
        tmpf, (float*)d_out, nullptr, rowptr, es, dinv, bt[7], nullptr, n, 0);
}